// Round 1
// baseline (2318.325 us; speedup 1.0000x reference)
//
#include <hip/hip_runtime.h>
#include <hip/hip_bf16.h>

// MVAE fused pipeline, round 4: split the latency-bound gather from the
// LDS-hungry decode.
// Round-3 post-mortem: k_poe_decode 890us, Occ 10.6%, VALU 30%, HBM 19%,
// FETCH 1.15 GB vs ~190 MB ideal -> random gather into gt (19.2 MB) misses
// L2+L3 (streamed traffic thrashes it) and the 63.5 KB LDS block (2/CU)
// leaves no TLP to hide ~900cy misses.
// Fixes: (1) k_poe: gather/PoE only, ZERO LDS -> high occupancy; z stashed
// f32 in ws. (2) nontemporal loads/stores on all streaming traffic to keep
// gt resident in L2/L3. (3) k_decode/k_encode: h1 in packed-bf16 REGISTERS
// (static-indexed via full unroll) instead of 32KB LDS.
// ws layout: [0..63B] dtype flag, [64B..] gt (N*64B), then zbuf (2N*6 f32).

typedef unsigned short u16;
typedef __hip_bfloat16 bf16;
typedef int iv4 __attribute__((ext_vector_type(4)));

__device__ __forceinline__ float blo(unsigned int x) {
    union { unsigned int i; float f; } v; v.i = x << 16; return v.f;
}
__device__ __forceinline__ float bhi(unsigned int x) {
    union { unsigned int i; float f; } v; v.i = x & 0xffff0000u; return v.f;
}
__device__ __forceinline__ u16 f2b16(float f) {
    __hip_bfloat16 h = __float2bfloat16(f);
    u16 u; __builtin_memcpy(&u, &h, 2); return u;
}
__device__ __forceinline__ float b2f(u16 u) {
    union { unsigned int i; float f; } v; v.i = ((unsigned int)u) << 16; return v.f;
}
__device__ __forceinline__ float swishf(float x) {
    return x / (1.0f + __expf(-x));
}
// dtype-flexible load/store (isb is wave-uniform -> scalar branch)
__device__ __forceinline__ float ldv(const void* p, size_t i, int isb) {
    return isb ? __bfloat162float(((const bf16*)p)[i]) : ((const float*)p)[i];
}
__device__ __forceinline__ void stv(void* p, size_t i, int isb, float v) {
    if (isb) ((bf16*)p)[i] = __float2bfloat16(v);
    else     ((float*)p)[i] = v;
}
// nontemporal variants for streaming (read-once / write-once) traffic
__device__ __forceinline__ float ldv_nt(const void* p, size_t i, int isb) {
    if (isb) return b2f(__builtin_nontemporal_load((const u16*)p + i));
    return __builtin_nontemporal_load((const float*)p + i);
}
__device__ __forceinline__ void stv_nt(void* p, size_t i, int isb, float v) {
    if (isb) { u16 b = f2b16(v); __builtin_nontemporal_store(b, (u16*)p + i); }
    else     __builtin_nontemporal_store(v, (float*)p + i);
}

// ---------------- Kernel 0: dtype detect ----------------
__global__ void k_detect(const unsigned int* __restrict__ obsw, int* __restrict__ flag) {
    unsigned int w = obsw[threadIdx.x];
    unsigned int e = (w >> 7) & 0xFFu;
    bool sane = (e >= 0x70u && e <= 0x87u);
    unsigned long long m = __ballot(sane);
    if (threadIdx.x == 0) flag[0] = (__popcll(m) >= 40) ? 1 : 0;
}

// ---------------- Kernel A: encoder ----------------
__global__ __launch_bounds__(256) void k_encode(
    const void* __restrict__ obs,
    const void* __restrict__ We1, const void* __restrict__ be1,
    const void* __restrict__ We2, const void* __restrict__ be2,
    const void* __restrict__ We3, const void* __restrict__ be3,
    const int* __restrict__ flag, u16* __restrict__ gt, int N)
{
    __shared__ float sW1[2 * 64];
    __shared__ float sb1[64];
    __shared__ float sW2[64 * 64];
    __shared__ float sb2[64];
    __shared__ float sW3[64 * 24];
    __shared__ float sb3[24];
    const int isb = flag[0];
    const int tid = threadIdx.x;
    for (int i = tid; i < 128; i += 256) sW1[i] = ldv(We1, i, isb);
    if (tid < 64) sb1[tid] = ldv(be1, tid, isb);
    for (int i = tid; i < 4096; i += 256) sW2[i] = ldv(We2, i, isb);
    if (tid < 64) sb2[tid] = ldv(be2, tid, isb);
    for (int i = tid; i < 1536; i += 256) sW3[i] = ldv(We3, i, isb);
    if (tid < 24) sb3[tid] = ldv(be3, tid, isb);
    __syncthreads();

    const int n = blockIdx.x * 256 + tid;
    if (n >= N) return;

    const float o0 = ldv_nt(obs, 2 * (size_t)n, isb);
    const float o1 = ldv_nt(obs, 2 * (size_t)n + 1, isb);

    // L1: 2 -> 64, into packed-bf16 registers (same bf16 round-trip as the
    // old LDS staging, so numerics unchanged)
    unsigned int hp[32];
#pragma unroll
    for (int j2 = 0; j2 < 32; ++j2) {
        float v0 = swishf(o0 * sW1[2 * j2]     + o1 * sW1[64 + 2 * j2]     + sb1[2 * j2]);
        float v1 = swishf(o0 * sW1[2 * j2 + 1] + o1 * sW1[64 + 2 * j2 + 1] + sb1[2 * j2 + 1]);
        hp[j2] = (unsigned int)f2b16(v0) | ((unsigned int)f2b16(v1) << 16);
    }

    // L2 (64->64, chunks of 16) streamed into L3 accumulator o[24]
    float o[24];
#pragma unroll
    for (int v = 0; v < 24; ++v) o[v] = sb3[v];

    for (int jc = 0; jc < 4; ++jc) {
        float acc[16];
#pragma unroll
        for (int k = 0; k < 16; ++k) acc[k] = sb2[jc * 16 + k];
#pragma unroll
        for (int i = 0; i < 64; ++i) {          // full unroll: hp index static
            const unsigned int w = hp[i >> 1];
            const float a = (i & 1) ? bhi(w) : blo(w);
            const float4* w4 = (const float4*)(sW2 + i * 64 + jc * 16);
#pragma unroll
            for (int k4 = 0; k4 < 4; ++k4) {
                float4 ww = w4[k4];
                acc[4 * k4 + 0] += a * ww.x; acc[4 * k4 + 1] += a * ww.y;
                acc[4 * k4 + 2] += a * ww.z; acc[4 * k4 + 3] += a * ww.w;
            }
        }
#pragma unroll
        for (int k = 0; k < 16; ++k) {
            const float a = swishf(acc[k]);
            const float4* w4 = (const float4*)(sW3 + (jc * 16 + k) * 24);
#pragma unroll
            for (int v4 = 0; v4 < 6; ++v4) {
                float4 w = w4[v4];
                o[4 * v4 + 0] += a * w.x; o[4 * v4 + 1] += a * w.y;
                o[4 * v4 + 2] += a * w.z; o[4 * v4 + 3] += a * w.w;
            }
        }
    }

    // pack gather-table entries (cached stores: kernel B gathers from gt)
    u16* g = gt + (size_t)n * 32;
#pragma unroll
    for (int mod = 0; mod < 2; ++mod) {
        float e[16];
#pragma unroll
        for (int l = 0; l < 6; ++l) {
            e[l]     = o[mod * 6 + l];       // mu
            e[6 + l] = o[12 + mod * 6 + l];  // logvar
        }
        e[12] = 0.f; e[13] = 0.f; e[14] = 0.f; e[15] = 0.f;
        unsigned int pk[8];
#pragma unroll
        for (int i = 0; i < 8; ++i)
            pk[i] = (unsigned int)f2b16(e[2 * i]) | ((unsigned int)f2b16(e[2 * i + 1]) << 16);
        *(int4*)(g + mod * 16)     = make_int4(pk[0], pk[1], pk[2], pk[3]);
        *(int4*)(g + mod * 16 + 8) = make_int4(pk[4], pk[5], pk[6], pk[7]);
    }
}

// ---------------- Kernel B1: PoE / reparameterize (no LDS, high occ) ----------------
__global__ __launch_bounds__(256, 4) void k_poe(
    const void* __restrict__ p,
    const void* __restrict__ eps_skip, const void* __restrict__ eps_poe,
    const int* __restrict__ nbs, const int* __restrict__ nbo,
    const int* __restrict__ flag, const u16* __restrict__ gt,
    float* __restrict__ zbuf, void* __restrict__ out, int N)
{
    const int isb = flag[0];
    const int idx = blockIdx.x * 256 + threadIdx.x;   // over 2N (n,mod) pairs
    const int n = idx >> 1;
    const int mod = idx & 1;
    if (n >= N) return;

    const bool skip = ldv_nt(p, n, isb) < 0.5f;

    const u16* g = gt + (size_t)n * 32 + mod * 16;
    int4 sa = *(const int4*)g;
    int2 sbv = *(const int2*)(g + 8);
    float mu[6], lv[6];
    mu[0] = blo(sa.x); mu[1] = bhi(sa.x); mu[2] = blo(sa.y);
    mu[3] = bhi(sa.y); mu[4] = blo(sa.z); mu[5] = bhi(sa.z);
    lv[0] = blo(sa.w); lv[1] = bhi(sa.w); lv[2] = blo(sbv.x);
    lv[3] = bhi(sbv.x); lv[4] = blo(sbv.y); lv[5] = bhi(sbv.y);

    float z[6], outmu[6], outlv[6];

    if (!skip) {
        float sT[6], sM[6];
        const float priorT = 1.0f / (1.0f + 1e-8f);
#pragma unroll
        for (int l = 0; l < 6; ++l) {
            float T = 1.0f / (__expf(lv[l]) + 1e-8f);
            sT[l] = priorT + T;
            sM[l] = mu[l] * T;
        }
        const iv4* ps = (const iv4*)(nbs + (size_t)idx * 64);
        const iv4* po = (const iv4*)(nbo + (size_t)idx * 64);
#pragma unroll 4
        for (int k4 = 0; k4 < 16; ++k4) {
            iv4 s4 = __builtin_nontemporal_load(ps + k4);   // streaming: keep out of L2/L3
            iv4 o4 = __builtin_nontemporal_load(po + k4);
            int ss[4] = { s4[0], s4[1], s4[2], s4[3] };
            int oo[4] = { o4[0], o4[1], o4[2], o4[3] };
#pragma unroll
            for (int u = 0; u < 4; ++u) {
                int sidx = ss[u]; if ((unsigned)sidx >= (unsigned)N) sidx = 0;
                int oidx = oo[u] & 1;
                const u16* e = gt + (size_t)sidx * 32 + oidx * 16;  // hot table: cached
                int4 a = *(const int4*)e;
                int2 b = *(const int2*)(e + 8);
                float m0 = blo(a.x), m1 = bhi(a.x), m2 = blo(a.y);
                float m3 = bhi(a.y), m4 = blo(a.z), m5 = bhi(a.z);
                float v0 = blo(a.w), v1 = bhi(a.w), v2 = blo(b.x);
                float v3 = bhi(b.x), v4 = blo(b.y), v5 = bhi(b.y);
                float T0 = 1.0f / (__expf(v0) + 1e-8f); sT[0] += T0; sM[0] += m0 * T0;
                float T1 = 1.0f / (__expf(v1) + 1e-8f); sT[1] += T1; sM[1] += m1 * T1;
                float T2 = 1.0f / (__expf(v2) + 1e-8f); sT[2] += T2; sM[2] += m2 * T2;
                float T3 = 1.0f / (__expf(v3) + 1e-8f); sT[3] += T3; sM[3] += m3 * T3;
                float T4 = 1.0f / (__expf(v4) + 1e-8f); sT[4] += T4; sM[4] += m4 * T4;
                float T5 = 1.0f / (__expf(v5) + 1e-8f); sT[5] += T5; sM[5] += m5 * T5;
            }
        }
#pragma unroll
        for (int l = 0; l < 6; ++l) {
            float pm = sM[l] / sT[l];
            outmu[l] = pm;
            outlv[l] = -__logf(sT[l]);
            z[l] = pm + ldv_nt(eps_poe, (size_t)idx * 6 + l, isb) * rsqrtf(sT[l]);
        }
    } else {
#pragma unroll
        for (int l = 0; l < 6; ++l) {
            outmu[l] = mu[l];
            outlv[l] = lv[l];
            z[l] = mu[l] + ldv_nt(eps_skip, (size_t)idx * 6 + l, isb) * __expf(0.5f * lv[l]);
        }
    }

    // z stash for k_decode (cached: reread within ~100us)
#pragma unroll
    for (int l = 0; l < 6; ++l) zbuf[(size_t)idx * 6 + l] = z[l];

    const size_t om = (size_t)N * 102 + (size_t)idx * 6;
    const size_t ol = (size_t)N * 114 + (size_t)idx * 6;
#pragma unroll
    for (int l = 0; l < 6; ++l) {
        stv_nt(out, om + l, isb, outmu[l]);
        stv_nt(out, ol + l, isb, outlv[l]);
    }
}

// ---------------- Kernel B2: decoder ----------------
__global__ __launch_bounds__(256) void k_decode(
    const void* __restrict__ Wd1, const void* __restrict__ bd1,
    const void* __restrict__ Wd2, const void* __restrict__ bd2,
    const void* __restrict__ Wd3, const void* __restrict__ bd3,
    const int* __restrict__ flag, const float* __restrict__ zbuf,
    void* __restrict__ out, int N)
{
    __shared__ float sW1[6 * 64];
    __shared__ float sb1[64];
    __shared__ float sW2[64 * 64];
    __shared__ float sb2[64];
    __shared__ float sW3[64 * 52];   // rows padded 51->52
    __shared__ float sb3[52];
    const int isb = flag[0];
    const int tid = threadIdx.x;
    for (int i = tid; i < 384; i += 256) sW1[i] = ldv(Wd1, i, isb);
    if (tid < 64) sb1[tid] = ldv(bd1, tid, isb);
    for (int i = tid; i < 4096; i += 256) sW2[i] = ldv(Wd2, i, isb);
    if (tid < 64) sb2[tid] = ldv(bd2, tid, isb);
    for (int t = tid; t < 64 * 52; t += 256) {
        int i = t / 52, v = t - i * 52;
        sW3[t] = (v < 51) ? ldv(Wd3, i * 51 + v, isb) : 0.f;
    }
    if (tid < 52) sb3[tid] = (tid < 51) ? ldv(bd3, tid, isb) : 0.f;
    __syncthreads();

    const int idx = blockIdx.x * 256 + tid;   // over 2N (n,mod) pairs
    const int n = idx >> 1;
    const int mod = idx & 1;
    if (n >= N) return;

    float z[6];
#pragma unroll
    for (int l = 0; l < 6; ++l) z[l] = zbuf[(size_t)idx * 6 + l];

    // L1: z -> h1, packed bf16 in registers (same rounding as old LDS path)
    unsigned int hp[32];
#pragma unroll
    for (int j4 = 0; j4 < 16; ++j4) {
        float a0 = sb1[4 * j4 + 0], a1 = sb1[4 * j4 + 1];
        float a2 = sb1[4 * j4 + 2], a3 = sb1[4 * j4 + 3];
#pragma unroll
        for (int l = 0; l < 6; ++l) {
            float4 w = ((const float4*)(sW1 + l * 64))[j4];
            a0 += z[l] * w.x; a1 += z[l] * w.y;
            a2 += z[l] * w.z; a3 += z[l] * w.w;
        }
        hp[2 * j4]     = (unsigned int)f2b16(swishf(a0)) | ((unsigned int)f2b16(swishf(a1)) << 16);
        hp[2 * j4 + 1] = (unsigned int)f2b16(swishf(a2)) | ((unsigned int)f2b16(swishf(a3)) << 16);
    }

    // L2 (chunks of 16) streamed into L3 accumulator r[52]
    float r[52];
#pragma unroll
    for (int v = 0; v < 52; ++v) r[v] = sb3[v];

    for (int jc = 0; jc < 4; ++jc) {
        float acc[16];
#pragma unroll
        for (int k = 0; k < 16; ++k) acc[k] = sb2[jc * 16 + k];
#pragma unroll
        for (int i = 0; i < 64; ++i) {          // full unroll: hp index static
            const unsigned int w = hp[i >> 1];
            const float a = (i & 1) ? bhi(w) : blo(w);
            const float4* w4 = (const float4*)(sW2 + i * 64 + jc * 16);
#pragma unroll
            for (int k4 = 0; k4 < 4; ++k4) {
                float4 ww = w4[k4];
                acc[4 * k4 + 0] += a * ww.x; acc[4 * k4 + 1] += a * ww.y;
                acc[4 * k4 + 2] += a * ww.z; acc[4 * k4 + 3] += a * ww.w;
            }
        }
#pragma unroll
        for (int k = 0; k < 16; ++k) {
            const float a = swishf(acc[k]);
            const float4* w4 = (const float4*)(sW3 + (jc * 16 + k) * 52);
#pragma unroll
            for (int v4 = 0; v4 < 13; ++v4) {
                float4 w = w4[v4];
                r[4 * v4 + 0] += a * w.x; r[4 * v4 + 1] += a * w.y;
                r[4 * v4 + 2] += a * w.z; r[4 * v4 + 3] += a * w.w;
            }
        }
    }

    const size_t ro = (size_t)n * 102 + (size_t)mod * 51;
#pragma unroll
    for (int v = 0; v < 51; ++v) stv_nt(out, ro + v, isb, r[v]);
}

extern "C" void kernel_launch(void* const* d_in, const int* in_sizes, int n_in,
                              void* d_out, int out_size, void* d_ws, size_t ws_size,
                              hipStream_t stream) {
    const int N = in_sizes[0] / 2;
    const void* obs      = d_in[0];
    const void* p        = d_in[1];
    const void* eps_skip = d_in[2];
    const void* eps_poe  = d_in[3];
    const int*  nbs      = (const int*)d_in[4];
    const int*  nbo      = (const int*)d_in[5];

    int* flag = (int*)d_ws;                                   // 64-byte flag region
    u16* gt   = (u16*)d_ws + 32;                              // gather table, N*64 bytes
    float* zbuf = (float*)((char*)d_ws + 64 + (size_t)N * 64); // z stash, 2N*6 f32

    dim3 blk(256);
    dim3 grdA((N + 255) / 256);
    dim3 grdB((2 * N + 255) / 256);
    hipLaunchKernelGGL(k_detect, dim3(1), dim3(64), 0, stream,
                       (const unsigned int*)obs, flag);
    hipLaunchKernelGGL(k_encode, grdA, blk, 0, stream,
                       obs, d_in[6], d_in[7], d_in[8], d_in[9], d_in[10], d_in[11],
                       flag, gt, N);
    hipLaunchKernelGGL(k_poe, grdB, blk, 0, stream,
                       p, eps_skip, eps_poe, nbs, nbo,
                       flag, gt, zbuf, (void*)d_out, N);
    hipLaunchKernelGGL(k_decode, grdB, blk, 0, stream,
                       d_in[12], d_in[13], d_in[14], d_in[15], d_in[16], d_in[17],
                       flag, zbuf, (void*)d_out, N);
}

// Round 2
// 1766.023 us; speedup vs baseline: 1.3127x; 1.3127x over previous
//
#include <hip/hip_runtime.h>
#include <hip/hip_bf16.h>

// MVAE fused pipeline, round 5: keep the kernel split, fix the NT-store bug.
// Round-4 post-mortem: k_decode 1523us with WRITE_SIZE 1.53 GB (12.5x ideal)
// -> __builtin_nontemporal_store on per-thread SCALAR stores (stride-204B
// across lanes) bypasses L2 write-combining; every 4B store streamed a
// partial line to HBM. Round 3 proved the SAME store pattern with cached
// stores combines to ~ideal (158 MB). Fix: all output stores cached again.
// NT hints kept ONLY on streaming READS (nbs/nbo/eps/p/obs) to protect the
// gt gather table's L2/L3 residency (reads fetch whole lines regardless,
// so NT-read has no amplification risk).
// ws layout: [0..63B] dtype flag, [64B..] gt (N*64B), then zbuf (2N*6 f32).

typedef unsigned short u16;
typedef __hip_bfloat16 bf16;
typedef int iv4 __attribute__((ext_vector_type(4)));

__device__ __forceinline__ float blo(unsigned int x) {
    union { unsigned int i; float f; } v; v.i = x << 16; return v.f;
}
__device__ __forceinline__ float bhi(unsigned int x) {
    union { unsigned int i; float f; } v; v.i = x & 0xffff0000u; return v.f;
}
__device__ __forceinline__ u16 f2b16(float f) {
    __hip_bfloat16 h = __float2bfloat16(f);
    u16 u; __builtin_memcpy(&u, &h, 2); return u;
}
__device__ __forceinline__ float b2f(u16 u) {
    union { unsigned int i; float f; } v; v.i = ((unsigned int)u) << 16; return v.f;
}
__device__ __forceinline__ float swishf(float x) {
    return x / (1.0f + __expf(-x));
}
// dtype-flexible load/store (isb is wave-uniform -> scalar branch)
__device__ __forceinline__ float ldv(const void* p, size_t i, int isb) {
    return isb ? __bfloat162float(((const bf16*)p)[i]) : ((const float*)p)[i];
}
__device__ __forceinline__ void stv(void* p, size_t i, int isb, float v) {
    if (isb) ((bf16*)p)[i] = __float2bfloat16(v);
    else     ((float*)p)[i] = v;
}
// nontemporal READ variant for streaming (read-once) traffic only
__device__ __forceinline__ float ldv_nt(const void* p, size_t i, int isb) {
    if (isb) return b2f(__builtin_nontemporal_load((const u16*)p + i));
    return __builtin_nontemporal_load((const float*)p + i);
}

// ---------------- Kernel 0: dtype detect ----------------
__global__ void k_detect(const unsigned int* __restrict__ obsw, int* __restrict__ flag) {
    unsigned int w = obsw[threadIdx.x];
    unsigned int e = (w >> 7) & 0xFFu;
    bool sane = (e >= 0x70u && e <= 0x87u);
    unsigned long long m = __ballot(sane);
    if (threadIdx.x == 0) flag[0] = (__popcll(m) >= 40) ? 1 : 0;
}

// ---------------- Kernel A: encoder ----------------
__global__ __launch_bounds__(256) void k_encode(
    const void* __restrict__ obs,
    const void* __restrict__ We1, const void* __restrict__ be1,
    const void* __restrict__ We2, const void* __restrict__ be2,
    const void* __restrict__ We3, const void* __restrict__ be3,
    const int* __restrict__ flag, u16* __restrict__ gt, int N)
{
    __shared__ float sW1[2 * 64];
    __shared__ float sb1[64];
    __shared__ float sW2[64 * 64];
    __shared__ float sb2[64];
    __shared__ float sW3[64 * 24];
    __shared__ float sb3[24];
    const int isb = flag[0];
    const int tid = threadIdx.x;
    for (int i = tid; i < 128; i += 256) sW1[i] = ldv(We1, i, isb);
    if (tid < 64) sb1[tid] = ldv(be1, tid, isb);
    for (int i = tid; i < 4096; i += 256) sW2[i] = ldv(We2, i, isb);
    if (tid < 64) sb2[tid] = ldv(be2, tid, isb);
    for (int i = tid; i < 1536; i += 256) sW3[i] = ldv(We3, i, isb);
    if (tid < 24) sb3[tid] = ldv(be3, tid, isb);
    __syncthreads();

    const int n = blockIdx.x * 256 + tid;
    if (n >= N) return;

    const float o0 = ldv_nt(obs, 2 * (size_t)n, isb);
    const float o1 = ldv_nt(obs, 2 * (size_t)n + 1, isb);

    // L1: 2 -> 64, into packed-bf16 registers (same bf16 round-trip as the
    // old LDS staging, so numerics unchanged)
    unsigned int hp[32];
#pragma unroll
    for (int j2 = 0; j2 < 32; ++j2) {
        float v0 = swishf(o0 * sW1[2 * j2]     + o1 * sW1[64 + 2 * j2]     + sb1[2 * j2]);
        float v1 = swishf(o0 * sW1[2 * j2 + 1] + o1 * sW1[64 + 2 * j2 + 1] + sb1[2 * j2 + 1]);
        hp[j2] = (unsigned int)f2b16(v0) | ((unsigned int)f2b16(v1) << 16);
    }

    // L2 (64->64, chunks of 16) streamed into L3 accumulator o[24]
    float o[24];
#pragma unroll
    for (int v = 0; v < 24; ++v) o[v] = sb3[v];

    for (int jc = 0; jc < 4; ++jc) {
        float acc[16];
#pragma unroll
        for (int k = 0; k < 16; ++k) acc[k] = sb2[jc * 16 + k];
#pragma unroll
        for (int i = 0; i < 64; ++i) {          // full unroll: hp index static
            const unsigned int w = hp[i >> 1];
            const float a = (i & 1) ? bhi(w) : blo(w);
            const float4* w4 = (const float4*)(sW2 + i * 64 + jc * 16);
#pragma unroll
            for (int k4 = 0; k4 < 4; ++k4) {
                float4 ww = w4[k4];
                acc[4 * k4 + 0] += a * ww.x; acc[4 * k4 + 1] += a * ww.y;
                acc[4 * k4 + 2] += a * ww.z; acc[4 * k4 + 3] += a * ww.w;
            }
        }
#pragma unroll
        for (int k = 0; k < 16; ++k) {
            const float a = swishf(acc[k]);
            const float4* w4 = (const float4*)(sW3 + (jc * 16 + k) * 24);
#pragma unroll
            for (int v4 = 0; v4 < 6; ++v4) {
                float4 w = w4[v4];
                o[4 * v4 + 0] += a * w.x; o[4 * v4 + 1] += a * w.y;
                o[4 * v4 + 2] += a * w.z; o[4 * v4 + 3] += a * w.w;
            }
        }
    }

    // pack gather-table entries (cached stores: kernel B gathers from gt)
    u16* g = gt + (size_t)n * 32;
#pragma unroll
    for (int mod = 0; mod < 2; ++mod) {
        float e[16];
#pragma unroll
        for (int l = 0; l < 6; ++l) {
            e[l]     = o[mod * 6 + l];       // mu
            e[6 + l] = o[12 + mod * 6 + l];  // logvar
        }
        e[12] = 0.f; e[13] = 0.f; e[14] = 0.f; e[15] = 0.f;
        unsigned int pk[8];
#pragma unroll
        for (int i = 0; i < 8; ++i)
            pk[i] = (unsigned int)f2b16(e[2 * i]) | ((unsigned int)f2b16(e[2 * i + 1]) << 16);
        *(int4*)(g + mod * 16)     = make_int4(pk[0], pk[1], pk[2], pk[3]);
        *(int4*)(g + mod * 16 + 8) = make_int4(pk[4], pk[5], pk[6], pk[7]);
    }
}

// ---------------- Kernel B1: PoE / reparameterize (no LDS, high occ) ----------------
__global__ __launch_bounds__(256, 4) void k_poe(
    const void* __restrict__ p,
    const void* __restrict__ eps_skip, const void* __restrict__ eps_poe,
    const int* __restrict__ nbs, const int* __restrict__ nbo,
    const int* __restrict__ flag, const u16* __restrict__ gt,
    float* __restrict__ zbuf, void* __restrict__ out, int N)
{
    const int isb = flag[0];
    const int idx = blockIdx.x * 256 + threadIdx.x;   // over 2N (n,mod) pairs
    const int n = idx >> 1;
    const int mod = idx & 1;
    if (n >= N) return;

    const bool skip = ldv_nt(p, n, isb) < 0.5f;

    const u16* g = gt + (size_t)n * 32 + mod * 16;
    int4 sa = *(const int4*)g;
    int2 sbv = *(const int2*)(g + 8);
    float mu[6], lv[6];
    mu[0] = blo(sa.x); mu[1] = bhi(sa.x); mu[2] = blo(sa.y);
    mu[3] = bhi(sa.y); mu[4] = blo(sa.z); mu[5] = bhi(sa.z);
    lv[0] = blo(sa.w); lv[1] = bhi(sa.w); lv[2] = blo(sbv.x);
    lv[3] = bhi(sbv.x); lv[4] = blo(sbv.y); lv[5] = bhi(sbv.y);

    float z[6], outmu[6], outlv[6];

    if (!skip) {
        float sT[6], sM[6];
        const float priorT = 1.0f / (1.0f + 1e-8f);
#pragma unroll
        for (int l = 0; l < 6; ++l) {
            float T = 1.0f / (__expf(lv[l]) + 1e-8f);
            sT[l] = priorT + T;
            sM[l] = mu[l] * T;
        }
        const iv4* ps = (const iv4*)(nbs + (size_t)idx * 64);
        const iv4* po = (const iv4*)(nbo + (size_t)idx * 64);
#pragma unroll 4
        for (int k4 = 0; k4 < 16; ++k4) {
            iv4 s4 = __builtin_nontemporal_load(ps + k4);   // streaming: keep out of L2/L3
            iv4 o4 = __builtin_nontemporal_load(po + k4);
            int ss[4] = { s4[0], s4[1], s4[2], s4[3] };
            int oo[4] = { o4[0], o4[1], o4[2], o4[3] };
#pragma unroll
            for (int u = 0; u < 4; ++u) {
                int sidx = ss[u]; if ((unsigned)sidx >= (unsigned)N) sidx = 0;
                int oidx = oo[u] & 1;
                const u16* e = gt + (size_t)sidx * 32 + oidx * 16;  // hot table: cached
                int4 a = *(const int4*)e;
                int2 b = *(const int2*)(e + 8);
                float m0 = blo(a.x), m1 = bhi(a.x), m2 = blo(a.y);
                float m3 = bhi(a.y), m4 = blo(a.z), m5 = bhi(a.z);
                float v0 = blo(a.w), v1 = bhi(a.w), v2 = blo(b.x);
                float v3 = bhi(b.x), v4 = blo(b.y), v5 = bhi(b.y);
                float T0 = 1.0f / (__expf(v0) + 1e-8f); sT[0] += T0; sM[0] += m0 * T0;
                float T1 = 1.0f / (__expf(v1) + 1e-8f); sT[1] += T1; sM[1] += m1 * T1;
                float T2 = 1.0f / (__expf(v2) + 1e-8f); sT[2] += T2; sM[2] += m2 * T2;
                float T3 = 1.0f / (__expf(v3) + 1e-8f); sT[3] += T3; sM[3] += m3 * T3;
                float T4 = 1.0f / (__expf(v4) + 1e-8f); sT[4] += T4; sM[4] += m4 * T4;
                float T5 = 1.0f / (__expf(v5) + 1e-8f); sT[5] += T5; sM[5] += m5 * T5;
            }
        }
#pragma unroll
        for (int l = 0; l < 6; ++l) {
            float pm = sM[l] / sT[l];
            outmu[l] = pm;
            outlv[l] = -__logf(sT[l]);
            z[l] = pm + ldv_nt(eps_poe, (size_t)idx * 6 + l, isb) * rsqrtf(sT[l]);
        }
    } else {
#pragma unroll
        for (int l = 0; l < 6; ++l) {
            outmu[l] = mu[l];
            outlv[l] = lv[l];
            z[l] = mu[l] + ldv_nt(eps_skip, (size_t)idx * 6 + l, isb) * __expf(0.5f * lv[l]);
        }
    }

    // z stash for k_decode (cached: reread within ~100us)
#pragma unroll
    for (int l = 0; l < 6; ++l) zbuf[(size_t)idx * 6 + l] = z[l];

    // cached stores: L2 write-combines the lane-strided scalars (round-3 proven)
    const size_t om = (size_t)N * 102 + (size_t)idx * 6;
    const size_t ol = (size_t)N * 114 + (size_t)idx * 6;
#pragma unroll
    for (int l = 0; l < 6; ++l) {
        stv(out, om + l, isb, outmu[l]);
        stv(out, ol + l, isb, outlv[l]);
    }
}

// ---------------- Kernel B2: decoder ----------------
__global__ __launch_bounds__(256) void k_decode(
    const void* __restrict__ Wd1, const void* __restrict__ bd1,
    const void* __restrict__ Wd2, const void* __restrict__ bd2,
    const void* __restrict__ Wd3, const void* __restrict__ bd3,
    const int* __restrict__ flag, const float* __restrict__ zbuf,
    void* __restrict__ out, int N)
{
    __shared__ float sW1[6 * 64];
    __shared__ float sb1[64];
    __shared__ float sW2[64 * 64];
    __shared__ float sb2[64];
    __shared__ float sW3[64 * 52];   // rows padded 51->52
    __shared__ float sb3[52];
    const int isb = flag[0];
    const int tid = threadIdx.x;
    for (int i = tid; i < 384; i += 256) sW1[i] = ldv(Wd1, i, isb);
    if (tid < 64) sb1[tid] = ldv(bd1, tid, isb);
    for (int i = tid; i < 4096; i += 256) sW2[i] = ldv(Wd2, i, isb);
    if (tid < 64) sb2[tid] = ldv(bd2, tid, isb);
    for (int t = tid; t < 64 * 52; t += 256) {
        int i = t / 52, v = t - i * 52;
        sW3[t] = (v < 51) ? ldv(Wd3, i * 51 + v, isb) : 0.f;
    }
    if (tid < 52) sb3[tid] = (tid < 51) ? ldv(bd3, tid, isb) : 0.f;
    __syncthreads();

    const int idx = blockIdx.x * 256 + tid;   // over 2N (n,mod) pairs
    const int n = idx >> 1;
    const int mod = idx & 1;
    if (n >= N) return;

    float z[6];
#pragma unroll
    for (int l = 0; l < 6; ++l) z[l] = zbuf[(size_t)idx * 6 + l];

    // L1: z -> h1, packed bf16 in registers (same rounding as old LDS path)
    unsigned int hp[32];
#pragma unroll
    for (int j4 = 0; j4 < 16; ++j4) {
        float a0 = sb1[4 * j4 + 0], a1 = sb1[4 * j4 + 1];
        float a2 = sb1[4 * j4 + 2], a3 = sb1[4 * j4 + 3];
#pragma unroll
        for (int l = 0; l < 6; ++l) {
            float4 w = ((const float4*)(sW1 + l * 64))[j4];
            a0 += z[l] * w.x; a1 += z[l] * w.y;
            a2 += z[l] * w.z; a3 += z[l] * w.w;
        }
        hp[2 * j4]     = (unsigned int)f2b16(swishf(a0)) | ((unsigned int)f2b16(swishf(a1)) << 16);
        hp[2 * j4 + 1] = (unsigned int)f2b16(swishf(a2)) | ((unsigned int)f2b16(swishf(a3)) << 16);
    }

    // L2 (chunks of 16) streamed into L3 accumulator r[52]
    float r[52];
#pragma unroll
    for (int v = 0; v < 52; ++v) r[v] = sb3[v];

    for (int jc = 0; jc < 4; ++jc) {
        float acc[16];
#pragma unroll
        for (int k = 0; k < 16; ++k) acc[k] = sb2[jc * 16 + k];
#pragma unroll
        for (int i = 0; i < 64; ++i) {          // full unroll: hp index static
            const unsigned int w = hp[i >> 1];
            const float a = (i & 1) ? bhi(w) : blo(w);
            const float4* w4 = (const float4*)(sW2 + i * 64 + jc * 16);
#pragma unroll
            for (int k4 = 0; k4 < 4; ++k4) {
                float4 ww = w4[k4];
                acc[4 * k4 + 0] += a * ww.x; acc[4 * k4 + 1] += a * ww.y;
                acc[4 * k4 + 2] += a * ww.z; acc[4 * k4 + 3] += a * ww.w;
            }
        }
#pragma unroll
        for (int k = 0; k < 16; ++k) {
            const float a = swishf(acc[k]);
            const float4* w4 = (const float4*)(sW3 + (jc * 16 + k) * 52);
#pragma unroll
            for (int v4 = 0; v4 < 13; ++v4) {
                float4 w = w4[v4];
                r[4 * v4 + 0] += a * w.x; r[4 * v4 + 1] += a * w.y;
                r[4 * v4 + 2] += a * w.z; r[4 * v4 + 3] += a * w.w;
            }
        }
    }

    // cached stores: L2 write-combines (round-3 proven, WRITE ~= ideal)
    const size_t ro = (size_t)n * 102 + (size_t)mod * 51;
#pragma unroll
    for (int v = 0; v < 51; ++v) stv(out, ro + v, isb, r[v]);
}

extern "C" void kernel_launch(void* const* d_in, const int* in_sizes, int n_in,
                              void* d_out, int out_size, void* d_ws, size_t ws_size,
                              hipStream_t stream) {
    const int N = in_sizes[0] / 2;
    const void* obs      = d_in[0];
    const void* p        = d_in[1];
    const void* eps_skip = d_in[2];
    const void* eps_poe  = d_in[3];
    const int*  nbs      = (const int*)d_in[4];
    const int*  nbo      = (const int*)d_in[5];

    int* flag = (int*)d_ws;                                   // 64-byte flag region
    u16* gt   = (u16*)d_ws + 32;                              // gather table, N*64 bytes
    float* zbuf = (float*)((char*)d_ws + 64 + (size_t)N * 64); // z stash, 2N*6 f32

    dim3 blk(256);
    dim3 grdA((N + 255) / 256);
    dim3 grdB((2 * N + 255) / 256);
    hipLaunchKernelGGL(k_detect, dim3(1), dim3(64), 0, stream,
                       (const unsigned int*)obs, flag);
    hipLaunchKernelGGL(k_encode, grdA, blk, 0, stream,
                       obs, d_in[6], d_in[7], d_in[8], d_in[9], d_in[10], d_in[11],
                       flag, gt, N);
    hipLaunchKernelGGL(k_poe, grdB, blk, 0, stream,
                       p, eps_skip, eps_poe, nbs, nbo,
                       flag, gt, zbuf, (void*)d_out, N);
    hipLaunchKernelGGL(k_decode, grdB, blk, 0, stream,
                       d_in[12], d_in[13], d_in[14], d_in[15], d_in[16], d_in[17],
                       flag, zbuf, (void*)d_out, N);
}

// Round 4
// 1416.185 us; speedup vs baseline: 1.6370x; 1.2470x over previous
//
#include <hip/hip_runtime.h>
#include <hip/hip_bf16.h>

// MVAE fused pipeline, round 6 RESUBMIT (round-3 bench was an infra failure:
// "container failed twice" during acquire; no pytest/absmax/profile output.
// Source re-audited: LDS 56.4KB/63.2KB under 64KiB limit, all bounds clamped,
// no capture-unsafe calls. Resubmitting unchanged to measure the theory.)
//
// Round-5 post-mortem: k_decode 1010us with HBM 2%, VALU 17%, 0 conflicts ->
// bound by instruction fetch: register-h1 forced FULL unroll of the 64-iter
// i-loop (rule: runtime-indexed reg arrays spill), ~10k inst ~ 80 KB code vs
// 32 KB I$. Fix: h1 back in LDS (round-3-proven own-column RAW, no barrier),
// i-loop rolled (unroll 4 only).
// New: S=2 sample-pair packing. The LDS-pipe floor is the per-wave weight
// BROADCAST ds_reads (~24k cyc/wave at S=1 -> ~370us). Packing two samples'
// h1 as bf16 pairs in one u32 halves LDS ops per sample (~185us floor) and
// one ds_read_b32 feeds both samples' FMAs. 128-thread blocks keep LDS
// (sh1 32KB + weights) at 2 blocks/CU. L3 k-loop fully unrolled so acc/r
// register arrays are static-indexed; total code ~27KB, fits I$.
// h2 stays f32 in registers -> numerics identical to round 5 (absmax 0.03125).
// ws layout: [0..63B] dtype flag, [64B..] gt (N*64B), then zbuf (2N*6 f32).

typedef unsigned short u16;
typedef unsigned int u32;
typedef __hip_bfloat16 bf16;
typedef int iv4 __attribute__((ext_vector_type(4)));

__device__ __forceinline__ float blo(u32 x) {
    union { u32 i; float f; } v; v.i = x << 16; return v.f;
}
__device__ __forceinline__ float bhi(u32 x) {
    union { u32 i; float f; } v; v.i = x & 0xffff0000u; return v.f;
}
__device__ __forceinline__ u16 f2b16(float f) {
    __hip_bfloat16 h = __float2bfloat16(f);
    u16 u; __builtin_memcpy(&u, &h, 2); return u;
}
__device__ __forceinline__ u32 pk2(float a, float b) {
    return (u32)f2b16(a) | ((u32)f2b16(b) << 16);
}
__device__ __forceinline__ float swishf(float x) {
    return x / (1.0f + __expf(-x));
}
// dtype-flexible load/store (isb is wave-uniform -> scalar branch)
__device__ __forceinline__ float ldv(const void* p, size_t i, int isb) {
    return isb ? __bfloat162float(((const bf16*)p)[i]) : ((const float*)p)[i];
}
__device__ __forceinline__ void stv(void* p, size_t i, int isb, float v) {
    if (isb) ((bf16*)p)[i] = __float2bfloat16(v);
    else     ((float*)p)[i] = v;
}
// nontemporal READ variant for streaming (read-once) traffic only
__device__ __forceinline__ float ldv_nt(const void* p, size_t i, int isb) {
    if (isb) { u16 b = __builtin_nontemporal_load((const u16*)p + i);
               union { u32 i; float f; } v; v.i = ((u32)b) << 16; return v.f; }
    return __builtin_nontemporal_load((const float*)p + i);
}

// ---------------- Kernel 0: dtype detect ----------------
__global__ void k_detect(const u32* __restrict__ obsw, int* __restrict__ flag) {
    u32 w = obsw[threadIdx.x];
    u32 e = (w >> 7) & 0xFFu;
    bool sane = (e >= 0x70u && e <= 0x87u);
    unsigned long long m = __ballot(sane);
    if (threadIdx.x == 0) flag[0] = (__popcll(m) >= 40) ? 1 : 0;
}

// ---------------- Kernel A: encoder (128 thr, S=2 samples/thread) ----------------
__global__ __launch_bounds__(128) void k_encode(
    const void* __restrict__ obs,
    const void* __restrict__ We1, const void* __restrict__ be1,
    const void* __restrict__ We2, const void* __restrict__ be2,
    const void* __restrict__ We3, const void* __restrict__ be3,
    const int* __restrict__ flag, u16* __restrict__ gt, int N)
{
    __shared__ float sW1[2 * 64];
    __shared__ float sb1[64];
    __shared__ float sW2[64 * 64];
    __shared__ float sb2[64];
    __shared__ float sW3[64 * 24];
    __shared__ float sb3[24];
    __shared__ u32 sh1[64 * 128];   // packed (A,B) bf16 pair, [feature][tid]
    const int isb = flag[0];
    const int tid = threadIdx.x;
    for (int i = tid; i < 128; i += 128) sW1[i] = ldv(We1, i, isb);
    if (tid < 64) sb1[tid] = ldv(be1, tid, isb);
    for (int i = tid; i < 4096; i += 128) sW2[i] = ldv(We2, i, isb);
    if (tid < 64) sb2[tid] = ldv(be2, tid, isb);
    for (int i = tid; i < 1536; i += 128) sW3[i] = ldv(We3, i, isb);
    if (tid < 24) sb3[tid] = ldv(be3, tid, isb);
    __syncthreads();

    const int base = blockIdx.x * 256;
    const int nA = base + tid;
    const int nB = base + 128 + tid;
    const int nAc = nA < N ? nA : N - 1;
    const int nBc = nB < N ? nB : N - 1;

    const float a0 = ldv_nt(obs, 2 * (size_t)nAc, isb);
    const float a1 = ldv_nt(obs, 2 * (size_t)nAc + 1, isb);
    const float b0 = ldv_nt(obs, 2 * (size_t)nBc, isb);
    const float b1 = ldv_nt(obs, 2 * (size_t)nBc + 1, isb);

    // L1: 2 -> 64, packed pair straight to LDS (own column, no barrier)
#pragma unroll 4
    for (int j = 0; j < 64; ++j) {
        float w0 = sW1[j], w1 = sW1[64 + j], bb = sb1[j];
        float vA = swishf(a0 * w0 + a1 * w1 + bb);
        float vB = swishf(b0 * w0 + b1 * w1 + bb);
        sh1[j * 128 + tid] = pk2(vA, vB);
    }

    float oA[24], oB[24];
#pragma unroll
    for (int v = 0; v < 24; ++v) { oA[v] = sb3[v]; oB[v] = sb3[v]; }

    for (int jc = 0; jc < 4; ++jc) {
        float accA[16], accB[16];
#pragma unroll
        for (int k = 0; k < 16; ++k) { accA[k] = sb2[jc * 16 + k]; accB[k] = accA[k]; }
#pragma unroll 4
        for (int i = 0; i < 64; ++i) {       // ROLLED (unroll 4): I$-safe
            const u32 hw = sh1[i * 128 + tid];
            const float aA = blo(hw), aB = bhi(hw);
            const float4* w4 = (const float4*)(sW2 + i * 64 + jc * 16);
#pragma unroll
            for (int k4 = 0; k4 < 4; ++k4) {
                float4 ww = w4[k4];
                accA[4 * k4 + 0] += aA * ww.x; accB[4 * k4 + 0] += aB * ww.x;
                accA[4 * k4 + 1] += aA * ww.y; accB[4 * k4 + 1] += aB * ww.y;
                accA[4 * k4 + 2] += aA * ww.z; accB[4 * k4 + 2] += aB * ww.z;
                accA[4 * k4 + 3] += aA * ww.w; accB[4 * k4 + 3] += aB * ww.w;
            }
        }
#pragma unroll
        for (int k = 0; k < 16; ++k) {       // h2 stays f32 in registers
            const float hA = swishf(accA[k]);
            const float hB = swishf(accB[k]);
            const float4* w4 = (const float4*)(sW3 + (jc * 16 + k) * 24);
#pragma unroll
            for (int v4 = 0; v4 < 6; ++v4) {
                float4 w = w4[v4];
                oA[4 * v4 + 0] += hA * w.x; oB[4 * v4 + 0] += hB * w.x;
                oA[4 * v4 + 1] += hA * w.y; oB[4 * v4 + 1] += hB * w.y;
                oA[4 * v4 + 2] += hA * w.z; oB[4 * v4 + 2] += hB * w.z;
                oA[4 * v4 + 3] += hA * w.w; oB[4 * v4 + 3] += hB * w.w;
            }
        }
    }

    // pack gather-table entries for each valid sample
    if (nA < N) {
        u16* g = gt + (size_t)nA * 32;
#pragma unroll
        for (int mod = 0; mod < 2; ++mod) {
            u32 pkk[8];
#pragma unroll
            for (int l = 0; l < 3; ++l)
                pkk[l] = pk2(oA[mod * 6 + 2 * l], oA[mod * 6 + 2 * l + 1]);
#pragma unroll
            for (int l = 0; l < 3; ++l)
                pkk[3 + l] = pk2(oA[12 + mod * 6 + 2 * l], oA[12 + mod * 6 + 2 * l + 1]);
            pkk[6] = 0u; pkk[7] = 0u;
            *(int4*)(g + mod * 16)     = make_int4(pkk[0], pkk[1], pkk[2], pkk[3]);
            *(int4*)(g + mod * 16 + 8) = make_int4(pkk[4], pkk[5], pkk[6], pkk[7]);
        }
    }
    if (nB < N) {
        u16* g = gt + (size_t)nB * 32;
#pragma unroll
        for (int mod = 0; mod < 2; ++mod) {
            u32 pkk[8];
#pragma unroll
            for (int l = 0; l < 3; ++l)
                pkk[l] = pk2(oB[mod * 6 + 2 * l], oB[mod * 6 + 2 * l + 1]);
#pragma unroll
            for (int l = 0; l < 3; ++l)
                pkk[3 + l] = pk2(oB[12 + mod * 6 + 2 * l], oB[12 + mod * 6 + 2 * l + 1]);
            pkk[6] = 0u; pkk[7] = 0u;
            *(int4*)(g + mod * 16)     = make_int4(pkk[0], pkk[1], pkk[2], pkk[3]);
            *(int4*)(g + mod * 16 + 8) = make_int4(pkk[4], pkk[5], pkk[6], pkk[7]);
        }
    }
}

// ---------------- Kernel B1: PoE / reparameterize (no LDS, high occ) ----------------
__global__ __launch_bounds__(256, 4) void k_poe(
    const void* __restrict__ p,
    const void* __restrict__ eps_skip, const void* __restrict__ eps_poe,
    const int* __restrict__ nbs, const int* __restrict__ nbo,
    const int* __restrict__ flag, const u16* __restrict__ gt,
    float* __restrict__ zbuf, void* __restrict__ out, int N)
{
    const int isb = flag[0];
    const int idx = blockIdx.x * 256 + threadIdx.x;   // over 2N (n,mod) pairs
    const int n = idx >> 1;
    const int mod = idx & 1;
    if (n >= N) return;

    const bool skip = ldv_nt(p, n, isb) < 0.5f;

    const u16* g = gt + (size_t)n * 32 + mod * 16;
    int4 sa = *(const int4*)g;
    int2 sbv = *(const int2*)(g + 8);
    float mu[6], lv[6];
    mu[0] = blo(sa.x); mu[1] = bhi(sa.x); mu[2] = blo(sa.y);
    mu[3] = bhi(sa.y); mu[4] = blo(sa.z); mu[5] = bhi(sa.z);
    lv[0] = blo(sa.w); lv[1] = bhi(sa.w); lv[2] = blo(sbv.x);
    lv[3] = bhi(sbv.x); lv[4] = blo(sbv.y); lv[5] = bhi(sbv.y);

    float z[6], outmu[6], outlv[6];

    if (!skip) {
        float sT[6], sM[6];
        const float priorT = 1.0f / (1.0f + 1e-8f);
#pragma unroll
        for (int l = 0; l < 6; ++l) {
            float T = 1.0f / (__expf(lv[l]) + 1e-8f);
            sT[l] = priorT + T;
            sM[l] = mu[l] * T;
        }
        const iv4* ps = (const iv4*)(nbs + (size_t)idx * 64);
        const iv4* po = (const iv4*)(nbo + (size_t)idx * 64);
#pragma unroll 4
        for (int k4 = 0; k4 < 16; ++k4) {
            iv4 s4 = __builtin_nontemporal_load(ps + k4);   // streaming: keep out of L2/L3
            iv4 o4 = __builtin_nontemporal_load(po + k4);
            int ss[4] = { s4[0], s4[1], s4[2], s4[3] };
            int oo[4] = { o4[0], o4[1], o4[2], o4[3] };
#pragma unroll
            for (int u = 0; u < 4; ++u) {
                int sidx = ss[u]; if ((unsigned)sidx >= (unsigned)N) sidx = 0;
                int oidx = oo[u] & 1;
                const u16* e = gt + (size_t)sidx * 32 + oidx * 16;  // hot table: cached
                int4 a = *(const int4*)e;
                int2 b = *(const int2*)(e + 8);
                float m0 = blo(a.x), m1 = bhi(a.x), m2 = blo(a.y);
                float m3 = bhi(a.y), m4 = blo(a.z), m5 = bhi(a.z);
                float v0 = blo(a.w), v1 = bhi(a.w), v2 = blo(b.x);
                float v3 = bhi(b.x), v4 = blo(b.y), v5 = bhi(b.y);
                float T0 = 1.0f / (__expf(v0) + 1e-8f); sT[0] += T0; sM[0] += m0 * T0;
                float T1 = 1.0f / (__expf(v1) + 1e-8f); sT[1] += T1; sM[1] += m1 * T1;
                float T2 = 1.0f / (__expf(v2) + 1e-8f); sT[2] += T2; sM[2] += m2 * T2;
                float T3 = 1.0f / (__expf(v3) + 1e-8f); sT[3] += T3; sM[3] += m3 * T3;
                float T4 = 1.0f / (__expf(v4) + 1e-8f); sT[4] += T4; sM[4] += m4 * T4;
                float T5 = 1.0f / (__expf(v5) + 1e-8f); sT[5] += T5; sM[5] += m5 * T5;
            }
        }
#pragma unroll
        for (int l = 0; l < 6; ++l) {
            float pm = sM[l] / sT[l];
            outmu[l] = pm;
            outlv[l] = -__logf(sT[l]);
            z[l] = pm + ldv_nt(eps_poe, (size_t)idx * 6 + l, isb) * rsqrtf(sT[l]);
        }
    } else {
#pragma unroll
        for (int l = 0; l < 6; ++l) {
            outmu[l] = mu[l];
            outlv[l] = lv[l];
            z[l] = mu[l] + ldv_nt(eps_skip, (size_t)idx * 6 + l, isb) * __expf(0.5f * lv[l]);
        }
    }

    // z stash for k_decode (cached: reread within ~100us)
#pragma unroll
    for (int l = 0; l < 6; ++l) zbuf[(size_t)idx * 6 + l] = z[l];

    // cached stores: L2 write-combines the lane-strided scalars (round-3/5 proven)
    const size_t om = (size_t)N * 102 + (size_t)idx * 6;
    const size_t ol = (size_t)N * 114 + (size_t)idx * 6;
#pragma unroll
    for (int l = 0; l < 6; ++l) {
        stv(out, om + l, isb, outmu[l]);
        stv(out, ol + l, isb, outlv[l]);
    }
}

// ---------------- Kernel B2: decoder (128 thr, S=2 pairs/thread) ----------------
__global__ __launch_bounds__(128) void k_decode(
    const void* __restrict__ Wd1, const void* __restrict__ bd1,
    const void* __restrict__ Wd2, const void* __restrict__ bd2,
    const void* __restrict__ Wd3, const void* __restrict__ bd3,
    const int* __restrict__ flag, const float* __restrict__ zbuf,
    void* __restrict__ out, int N)
{
    __shared__ float sW1[6 * 64];
    __shared__ float sb1[64];
    __shared__ float sW2[64 * 64];
    __shared__ float sb2[64];
    __shared__ float sW3[64 * 52];   // rows padded 51->52
    __shared__ float sb3[52];
    __shared__ u32 sh1[64 * 128];    // packed (A,B) bf16 pair, [feature][tid]
    const int isb = flag[0];
    const int tid = threadIdx.x;
    for (int i = tid; i < 384; i += 128) sW1[i] = ldv(Wd1, i, isb);
    if (tid < 64) sb1[tid] = ldv(bd1, tid, isb);
    for (int i = tid; i < 4096; i += 128) sW2[i] = ldv(Wd2, i, isb);
    if (tid < 64) sb2[tid] = ldv(bd2, tid, isb);
    for (int t = tid; t < 64 * 52; t += 128) {
        int i = t / 52, v = t - i * 52;
        sW3[t] = (v < 51) ? ldv(Wd3, i * 51 + v, isb) : 0.f;
    }
    if (tid < 52) sb3[tid] = (tid < 51) ? ldv(bd3, tid, isb) : 0.f;
    __syncthreads();

    const int twoN = 2 * N;
    const int base = blockIdx.x * 256;
    const int idxA = base + tid;
    const int idxB = base + 128 + tid;
    const int iAc = idxA < twoN ? idxA : twoN - 1;
    const int iBc = idxB < twoN ? idxB : twoN - 1;

    float zA[6], zB[6];
#pragma unroll
    for (int l = 0; l < 6; ++l) {
        zA[l] = zbuf[(size_t)iAc * 6 + l];
        zB[l] = zbuf[(size_t)iBc * 6 + l];
    }

    // L1: z -> h1, packed pair to LDS (own column, no barrier needed)
#pragma unroll 4
    for (int j4 = 0; j4 < 16; ++j4) {
        float A0 = sb1[4 * j4 + 0], A1 = sb1[4 * j4 + 1];
        float A2 = sb1[4 * j4 + 2], A3 = sb1[4 * j4 + 3];
        float B0 = A0, B1 = A1, B2 = A2, B3 = A3;
#pragma unroll
        for (int l = 0; l < 6; ++l) {
            float4 w = ((const float4*)(sW1 + l * 64))[j4];
            A0 += zA[l] * w.x; B0 += zB[l] * w.x;
            A1 += zA[l] * w.y; B1 += zB[l] * w.y;
            A2 += zA[l] * w.z; B2 += zB[l] * w.z;
            A3 += zA[l] * w.w; B3 += zB[l] * w.w;
        }
        sh1[(4 * j4 + 0) * 128 + tid] = pk2(swishf(A0), swishf(B0));
        sh1[(4 * j4 + 1) * 128 + tid] = pk2(swishf(A1), swishf(B1));
        sh1[(4 * j4 + 2) * 128 + tid] = pk2(swishf(A2), swishf(B2));
        sh1[(4 * j4 + 3) * 128 + tid] = pk2(swishf(A3), swishf(B3));
    }

    float rA[52], rB[52];
#pragma unroll
    for (int v = 0; v < 52; ++v) { rA[v] = sb3[v]; rB[v] = sb3[v]; }

    for (int jc = 0; jc < 4; ++jc) {
        float accA[16], accB[16];
#pragma unroll
        for (int k = 0; k < 16; ++k) { accA[k] = sb2[jc * 16 + k]; accB[k] = accA[k]; }
#pragma unroll 4
        for (int i = 0; i < 64; ++i) {       // ROLLED (unroll 4): I$-safe
            const u32 hw = sh1[i * 128 + tid];
            const float aA = blo(hw), aB = bhi(hw);
            const float4* w4 = (const float4*)(sW2 + i * 64 + jc * 16);
#pragma unroll
            for (int k4 = 0; k4 < 4; ++k4) {
                float4 ww = w4[k4];
                accA[4 * k4 + 0] += aA * ww.x; accB[4 * k4 + 0] += aB * ww.x;
                accA[4 * k4 + 1] += aA * ww.y; accB[4 * k4 + 1] += aB * ww.y;
                accA[4 * k4 + 2] += aA * ww.z; accB[4 * k4 + 2] += aB * ww.z;
                accA[4 * k4 + 3] += aA * ww.w; accB[4 * k4 + 3] += aB * ww.w;
            }
        }
#pragma unroll
        for (int k = 0; k < 16; ++k) {       // h2 stays f32: numerics unchanged
            const float hA = swishf(accA[k]);
            const float hB = swishf(accB[k]);
            const float4* w4 = (const float4*)(sW3 + (jc * 16 + k) * 52);
#pragma unroll
            for (int v4 = 0; v4 < 13; ++v4) {
                float4 w = w4[v4];
                rA[4 * v4 + 0] += hA * w.x; rB[4 * v4 + 0] += hB * w.x;
                rA[4 * v4 + 1] += hA * w.y; rB[4 * v4 + 1] += hB * w.y;
                rA[4 * v4 + 2] += hA * w.z; rB[4 * v4 + 2] += hB * w.z;
                rA[4 * v4 + 3] += hA * w.w; rB[4 * v4 + 3] += hB * w.w;
            }
        }
    }

    // cached stores (L2 write-combines; round-5 proven WRITE ~= ideal)
    if (idxA < twoN) {
        const int n = idxA >> 1, mod = idxA & 1;
        const size_t ro = (size_t)n * 102 + (size_t)mod * 51;
#pragma unroll
        for (int v = 0; v < 51; ++v) stv(out, ro + v, isb, rA[v]);
    }
    if (idxB < twoN) {
        const int n = idxB >> 1, mod = idxB & 1;
        const size_t ro = (size_t)n * 102 + (size_t)mod * 51;
#pragma unroll
        for (int v = 0; v < 51; ++v) stv(out, ro + v, isb, rB[v]);
    }
}

extern "C" void kernel_launch(void* const* d_in, const int* in_sizes, int n_in,
                              void* d_out, int out_size, void* d_ws, size_t ws_size,
                              hipStream_t stream) {
    const int N = in_sizes[0] / 2;
    const void* obs      = d_in[0];
    const void* p        = d_in[1];
    const void* eps_skip = d_in[2];
    const void* eps_poe  = d_in[3];
    const int*  nbs      = (const int*)d_in[4];
    const int*  nbo      = (const int*)d_in[5];

    int* flag = (int*)d_ws;                                   // 64-byte flag region
    u16* gt   = (u16*)d_ws + 32;                              // gather table, N*64 bytes
    float* zbuf = (float*)((char*)d_ws + 64 + (size_t)N * 64); // z stash, 2N*6 f32

    dim3 grdA((N + 255) / 256);        // 256 samples per 128-thread block (S=2)
    dim3 grdP((2 * N + 255) / 256);    // k_poe: 256 threads, 1 pair each
    dim3 grdD((2 * N + 255) / 256);    // 256 pairs per 128-thread block (S=2)
    hipLaunchKernelGGL(k_detect, dim3(1), dim3(64), 0, stream,
                       (const unsigned int*)obs, flag);
    hipLaunchKernelGGL(k_encode, grdA, dim3(128), 0, stream,
                       obs, d_in[6], d_in[7], d_in[8], d_in[9], d_in[10], d_in[11],
                       flag, gt, N);
    hipLaunchKernelGGL(k_poe, grdP, dim3(256), 0, stream,
                       p, eps_skip, eps_poe, nbs, nbo,
                       flag, gt, zbuf, (void*)d_out, N);
    hipLaunchKernelGGL(k_decode, grdD, dim3(128), 0, stream,
                       d_in[12], d_in[13], d_in[14], d_in[15], d_in[16], d_in[17],
                       flag, zbuf, (void*)d_out, N);
}

// Round 5
// 1414.309 us; speedup vs baseline: 1.6392x; 1.0013x over previous
//
#include <hip/hip_runtime.h>
#include <hip/hip_bf16.h>

// MVAE fused pipeline, round 7: unlock 512 VGPRs (kill the S=2 spills).
// Round-6 post-mortem: k_decode 678us, VGPR=256, WRITE 675MB (ideal ~165MB),
// FETCH 80MB (ideal ~15MB) -> ~510MB scratch spill traffic. S=2 needs
// rA[52]+rB[52]+accA[16]+accB[16]=136 accum regs + temps (~300); bare
// __launch_bounds__(128) let the compiler target 2 waves/SIMD = 256-VGPR cap
// -> spill. Occupancy is ALREADY LDS-capped at 2 blocks/CU x 2 waves =
// 4 waves/CU = 1 wave/SIMD (63.5KB LDS; measured Occ 10.6% confirms), and at
// 1 wave/SIMD the VGPR budget is 512. So __launch_bounds__(128, 1) unlocks
// 512 VGPRs at ZERO occupancy cost. Single change this round.
// Remaining decode floor: ~2100 LDS reads/wave x ~12cyc x 18.3 waves/CU
// ~= 190us LDS-issue; predict decode ~300-380us.
// ws layout: [0..63B] dtype flag, [64B..] gt (N*64B), then zbuf (2N*6 f32).

typedef unsigned short u16;
typedef unsigned int u32;
typedef __hip_bfloat16 bf16;
typedef int iv4 __attribute__((ext_vector_type(4)));

__device__ __forceinline__ float blo(u32 x) {
    union { u32 i; float f; } v; v.i = x << 16; return v.f;
}
__device__ __forceinline__ float bhi(u32 x) {
    union { u32 i; float f; } v; v.i = x & 0xffff0000u; return v.f;
}
__device__ __forceinline__ u16 f2b16(float f) {
    __hip_bfloat16 h = __float2bfloat16(f);
    u16 u; __builtin_memcpy(&u, &h, 2); return u;
}
__device__ __forceinline__ u32 pk2(float a, float b) {
    return (u32)f2b16(a) | ((u32)f2b16(b) << 16);
}
__device__ __forceinline__ float swishf(float x) {
    return x / (1.0f + __expf(-x));
}
// dtype-flexible load/store (isb is wave-uniform -> scalar branch)
__device__ __forceinline__ float ldv(const void* p, size_t i, int isb) {
    return isb ? __bfloat162float(((const bf16*)p)[i]) : ((const float*)p)[i];
}
__device__ __forceinline__ void stv(void* p, size_t i, int isb, float v) {
    if (isb) ((bf16*)p)[i] = __float2bfloat16(v);
    else     ((float*)p)[i] = v;
}
// nontemporal READ variant for streaming (read-once) traffic only
__device__ __forceinline__ float ldv_nt(const void* p, size_t i, int isb) {
    if (isb) { u16 b = __builtin_nontemporal_load((const u16*)p + i);
               union { u32 i; float f; } v; v.i = ((u32)b) << 16; return v.f; }
    return __builtin_nontemporal_load((const float*)p + i);
}

// ---------------- Kernel 0: dtype detect ----------------
__global__ void k_detect(const u32* __restrict__ obsw, int* __restrict__ flag) {
    u32 w = obsw[threadIdx.x];
    u32 e = (w >> 7) & 0xFFu;
    bool sane = (e >= 0x70u && e <= 0x87u);
    unsigned long long m = __ballot(sane);
    if (threadIdx.x == 0) flag[0] = (__popcll(m) >= 40) ? 1 : 0;
}

// ---------------- Kernel A: encoder (128 thr, S=2 samples/thread) ----------------
__global__ __launch_bounds__(128, 1) void k_encode(
    const void* __restrict__ obs,
    const void* __restrict__ We1, const void* __restrict__ be1,
    const void* __restrict__ We2, const void* __restrict__ be2,
    const void* __restrict__ We3, const void* __restrict__ be3,
    const int* __restrict__ flag, u16* __restrict__ gt, int N)
{
    __shared__ float sW1[2 * 64];
    __shared__ float sb1[64];
    __shared__ float sW2[64 * 64];
    __shared__ float sb2[64];
    __shared__ float sW3[64 * 24];
    __shared__ float sb3[24];
    __shared__ u32 sh1[64 * 128];   // packed (A,B) bf16 pair, [feature][tid]
    const int isb = flag[0];
    const int tid = threadIdx.x;
    for (int i = tid; i < 128; i += 128) sW1[i] = ldv(We1, i, isb);
    if (tid < 64) sb1[tid] = ldv(be1, tid, isb);
    for (int i = tid; i < 4096; i += 128) sW2[i] = ldv(We2, i, isb);
    if (tid < 64) sb2[tid] = ldv(be2, tid, isb);
    for (int i = tid; i < 1536; i += 128) sW3[i] = ldv(We3, i, isb);
    if (tid < 24) sb3[tid] = ldv(be3, tid, isb);
    __syncthreads();

    const int base = blockIdx.x * 256;
    const int nA = base + tid;
    const int nB = base + 128 + tid;
    const int nAc = nA < N ? nA : N - 1;
    const int nBc = nB < N ? nB : N - 1;

    const float a0 = ldv_nt(obs, 2 * (size_t)nAc, isb);
    const float a1 = ldv_nt(obs, 2 * (size_t)nAc + 1, isb);
    const float b0 = ldv_nt(obs, 2 * (size_t)nBc, isb);
    const float b1 = ldv_nt(obs, 2 * (size_t)nBc + 1, isb);

    // L1: 2 -> 64, packed pair straight to LDS (own column, no barrier)
#pragma unroll 4
    for (int j = 0; j < 64; ++j) {
        float w0 = sW1[j], w1 = sW1[64 + j], bb = sb1[j];
        float vA = swishf(a0 * w0 + a1 * w1 + bb);
        float vB = swishf(b0 * w0 + b1 * w1 + bb);
        sh1[j * 128 + tid] = pk2(vA, vB);
    }

    float oA[24], oB[24];
#pragma unroll
    for (int v = 0; v < 24; ++v) { oA[v] = sb3[v]; oB[v] = sb3[v]; }

    for (int jc = 0; jc < 4; ++jc) {
        float accA[16], accB[16];
#pragma unroll
        for (int k = 0; k < 16; ++k) { accA[k] = sb2[jc * 16 + k]; accB[k] = accA[k]; }
#pragma unroll 4
        for (int i = 0; i < 64; ++i) {       // ROLLED (unroll 4): I$-safe
            const u32 hw = sh1[i * 128 + tid];
            const float aA = blo(hw), aB = bhi(hw);
            const float4* w4 = (const float4*)(sW2 + i * 64 + jc * 16);
#pragma unroll
            for (int k4 = 0; k4 < 4; ++k4) {
                float4 ww = w4[k4];
                accA[4 * k4 + 0] += aA * ww.x; accB[4 * k4 + 0] += aB * ww.x;
                accA[4 * k4 + 1] += aA * ww.y; accB[4 * k4 + 1] += aB * ww.y;
                accA[4 * k4 + 2] += aA * ww.z; accB[4 * k4 + 2] += aB * ww.z;
                accA[4 * k4 + 3] += aA * ww.w; accB[4 * k4 + 3] += aB * ww.w;
            }
        }
#pragma unroll
        for (int k = 0; k < 16; ++k) {       // h2 stays f32 in registers
            const float hA = swishf(accA[k]);
            const float hB = swishf(accB[k]);
            const float4* w4 = (const float4*)(sW3 + (jc * 16 + k) * 24);
#pragma unroll
            for (int v4 = 0; v4 < 6; ++v4) {
                float4 w = w4[v4];
                oA[4 * v4 + 0] += hA * w.x; oB[4 * v4 + 0] += hB * w.x;
                oA[4 * v4 + 1] += hA * w.y; oB[4 * v4 + 1] += hB * w.y;
                oA[4 * v4 + 2] += hA * w.z; oB[4 * v4 + 2] += hB * w.z;
                oA[4 * v4 + 3] += hA * w.w; oB[4 * v4 + 3] += hB * w.w;
            }
        }
    }

    // pack gather-table entries for each valid sample
    if (nA < N) {
        u16* g = gt + (size_t)nA * 32;
#pragma unroll
        for (int mod = 0; mod < 2; ++mod) {
            u32 pkk[8];
#pragma unroll
            for (int l = 0; l < 3; ++l)
                pkk[l] = pk2(oA[mod * 6 + 2 * l], oA[mod * 6 + 2 * l + 1]);
#pragma unroll
            for (int l = 0; l < 3; ++l)
                pkk[3 + l] = pk2(oA[12 + mod * 6 + 2 * l], oA[12 + mod * 6 + 2 * l + 1]);
            pkk[6] = 0u; pkk[7] = 0u;
            *(int4*)(g + mod * 16)     = make_int4(pkk[0], pkk[1], pkk[2], pkk[3]);
            *(int4*)(g + mod * 16 + 8) = make_int4(pkk[4], pkk[5], pkk[6], pkk[7]);
        }
    }
    if (nB < N) {
        u16* g = gt + (size_t)nB * 32;
#pragma unroll
        for (int mod = 0; mod < 2; ++mod) {
            u32 pkk[8];
#pragma unroll
            for (int l = 0; l < 3; ++l)
                pkk[l] = pk2(oB[mod * 6 + 2 * l], oB[mod * 6 + 2 * l + 1]);
#pragma unroll
            for (int l = 0; l < 3; ++l)
                pkk[3 + l] = pk2(oB[12 + mod * 6 + 2 * l], oB[12 + mod * 6 + 2 * l + 1]);
            pkk[6] = 0u; pkk[7] = 0u;
            *(int4*)(g + mod * 16)     = make_int4(pkk[0], pkk[1], pkk[2], pkk[3]);
            *(int4*)(g + mod * 16 + 8) = make_int4(pkk[4], pkk[5], pkk[6], pkk[7]);
        }
    }
}

// ---------------- Kernel B1: PoE / reparameterize (no LDS, high occ) ----------------
__global__ __launch_bounds__(256, 4) void k_poe(
    const void* __restrict__ p,
    const void* __restrict__ eps_skip, const void* __restrict__ eps_poe,
    const int* __restrict__ nbs, const int* __restrict__ nbo,
    const int* __restrict__ flag, const u16* __restrict__ gt,
    float* __restrict__ zbuf, void* __restrict__ out, int N)
{
    const int isb = flag[0];
    const int idx = blockIdx.x * 256 + threadIdx.x;   // over 2N (n,mod) pairs
    const int n = idx >> 1;
    const int mod = idx & 1;
    if (n >= N) return;

    const bool skip = ldv_nt(p, n, isb) < 0.5f;

    const u16* g = gt + (size_t)n * 32 + mod * 16;
    int4 sa = *(const int4*)g;
    int2 sbv = *(const int2*)(g + 8);
    float mu[6], lv[6];
    mu[0] = blo(sa.x); mu[1] = bhi(sa.x); mu[2] = blo(sa.y);
    mu[3] = bhi(sa.y); mu[4] = blo(sa.z); mu[5] = bhi(sa.z);
    lv[0] = blo(sa.w); lv[1] = bhi(sa.w); lv[2] = blo(sbv.x);
    lv[3] = bhi(sbv.x); lv[4] = blo(sbv.y); lv[5] = bhi(sbv.y);

    float z[6], outmu[6], outlv[6];

    if (!skip) {
        float sT[6], sM[6];
        const float priorT = 1.0f / (1.0f + 1e-8f);
#pragma unroll
        for (int l = 0; l < 6; ++l) {
            float T = 1.0f / (__expf(lv[l]) + 1e-8f);
            sT[l] = priorT + T;
            sM[l] = mu[l] * T;
        }
        const iv4* ps = (const iv4*)(nbs + (size_t)idx * 64);
        const iv4* po = (const iv4*)(nbo + (size_t)idx * 64);
#pragma unroll 4
        for (int k4 = 0; k4 < 16; ++k4) {
            iv4 s4 = __builtin_nontemporal_load(ps + k4);   // streaming: keep out of L2/L3
            iv4 o4 = __builtin_nontemporal_load(po + k4);
            int ss[4] = { s4[0], s4[1], s4[2], s4[3] };
            int oo[4] = { o4[0], o4[1], o4[2], o4[3] };
#pragma unroll
            for (int u = 0; u < 4; ++u) {
                int sidx = ss[u]; if ((unsigned)sidx >= (unsigned)N) sidx = 0;
                int oidx = oo[u] & 1;
                const u16* e = gt + (size_t)sidx * 32 + oidx * 16;  // hot table: cached
                int4 a = *(const int4*)e;
                int2 b = *(const int2*)(e + 8);
                float m0 = blo(a.x), m1 = bhi(a.x), m2 = blo(a.y);
                float m3 = bhi(a.y), m4 = blo(a.z), m5 = bhi(a.z);
                float v0 = blo(a.w), v1 = bhi(a.w), v2 = blo(b.x);
                float v3 = bhi(b.x), v4 = blo(b.y), v5 = bhi(b.y);
                float T0 = 1.0f / (__expf(v0) + 1e-8f); sT[0] += T0; sM[0] += m0 * T0;
                float T1 = 1.0f / (__expf(v1) + 1e-8f); sT[1] += T1; sM[1] += m1 * T1;
                float T2 = 1.0f / (__expf(v2) + 1e-8f); sT[2] += T2; sM[2] += m2 * T2;
                float T3 = 1.0f / (__expf(v3) + 1e-8f); sT[3] += T3; sM[3] += m3 * T3;
                float T4 = 1.0f / (__expf(v4) + 1e-8f); sT[4] += T4; sM[4] += m4 * T4;
                float T5 = 1.0f / (__expf(v5) + 1e-8f); sT[5] += T5; sM[5] += m5 * T5;
            }
        }
#pragma unroll
        for (int l = 0; l < 6; ++l) {
            float pm = sM[l] / sT[l];
            outmu[l] = pm;
            outlv[l] = -__logf(sT[l]);
            z[l] = pm + ldv_nt(eps_poe, (size_t)idx * 6 + l, isb) * rsqrtf(sT[l]);
        }
    } else {
#pragma unroll
        for (int l = 0; l < 6; ++l) {
            outmu[l] = mu[l];
            outlv[l] = lv[l];
            z[l] = mu[l] + ldv_nt(eps_skip, (size_t)idx * 6 + l, isb) * __expf(0.5f * lv[l]);
        }
    }

    // z stash for k_decode (cached: reread within ~100us)
#pragma unroll
    for (int l = 0; l < 6; ++l) zbuf[(size_t)idx * 6 + l] = z[l];

    // cached stores: L2 write-combines the lane-strided scalars (round-3/5 proven)
    const size_t om = (size_t)N * 102 + (size_t)idx * 6;
    const size_t ol = (size_t)N * 114 + (size_t)idx * 6;
#pragma unroll
    for (int l = 0; l < 6; ++l) {
        stv(out, om + l, isb, outmu[l]);
        stv(out, ol + l, isb, outlv[l]);
    }
}

// ---------------- Kernel B2: decoder (128 thr, S=2 pairs/thread) ----------------
__global__ __launch_bounds__(128, 1) void k_decode(
    const void* __restrict__ Wd1, const void* __restrict__ bd1,
    const void* __restrict__ Wd2, const void* __restrict__ bd2,
    const void* __restrict__ Wd3, const void* __restrict__ bd3,
    const int* __restrict__ flag, const float* __restrict__ zbuf,
    void* __restrict__ out, int N)
{
    __shared__ float sW1[6 * 64];
    __shared__ float sb1[64];
    __shared__ float sW2[64 * 64];
    __shared__ float sb2[64];
    __shared__ float sW3[64 * 52];   // rows padded 51->52
    __shared__ float sb3[52];
    __shared__ u32 sh1[64 * 128];    // packed (A,B) bf16 pair, [feature][tid]
    const int isb = flag[0];
    const int tid = threadIdx.x;
    for (int i = tid; i < 384; i += 128) sW1[i] = ldv(Wd1, i, isb);
    if (tid < 64) sb1[tid] = ldv(bd1, tid, isb);
    for (int i = tid; i < 4096; i += 128) sW2[i] = ldv(Wd2, i, isb);
    if (tid < 64) sb2[tid] = ldv(bd2, tid, isb);
    for (int t = tid; t < 64 * 52; t += 128) {
        int i = t / 52, v = t - i * 52;
        sW3[t] = (v < 51) ? ldv(Wd3, i * 51 + v, isb) : 0.f;
    }
    if (tid < 52) sb3[tid] = (tid < 51) ? ldv(bd3, tid, isb) : 0.f;
    __syncthreads();

    const int twoN = 2 * N;
    const int base = blockIdx.x * 256;
    const int idxA = base + tid;
    const int idxB = base + 128 + tid;
    const int iAc = idxA < twoN ? idxA : twoN - 1;
    const int iBc = idxB < twoN ? idxB : twoN - 1;

    float zA[6], zB[6];
#pragma unroll
    for (int l = 0; l < 6; ++l) {
        zA[l] = zbuf[(size_t)iAc * 6 + l];
        zB[l] = zbuf[(size_t)iBc * 6 + l];
    }

    // L1: z -> h1, packed pair to LDS (own column, no barrier needed)
#pragma unroll 4
    for (int j4 = 0; j4 < 16; ++j4) {
        float A0 = sb1[4 * j4 + 0], A1 = sb1[4 * j4 + 1];
        float A2 = sb1[4 * j4 + 2], A3 = sb1[4 * j4 + 3];
        float B0 = A0, B1 = A1, B2 = A2, B3 = A3;
#pragma unroll
        for (int l = 0; l < 6; ++l) {
            float4 w = ((const float4*)(sW1 + l * 64))[j4];
            A0 += zA[l] * w.x; B0 += zB[l] * w.x;
            A1 += zA[l] * w.y; B1 += zB[l] * w.y;
            A2 += zA[l] * w.z; B2 += zB[l] * w.z;
            A3 += zA[l] * w.w; B3 += zB[l] * w.w;
        }
        sh1[(4 * j4 + 0) * 128 + tid] = pk2(swishf(A0), swishf(B0));
        sh1[(4 * j4 + 1) * 128 + tid] = pk2(swishf(A1), swishf(B1));
        sh1[(4 * j4 + 2) * 128 + tid] = pk2(swishf(A2), swishf(B2));
        sh1[(4 * j4 + 3) * 128 + tid] = pk2(swishf(A3), swishf(B3));
    }

    float rA[52], rB[52];
#pragma unroll
    for (int v = 0; v < 52; ++v) { rA[v] = sb3[v]; rB[v] = sb3[v]; }

    for (int jc = 0; jc < 4; ++jc) {
        float accA[16], accB[16];
#pragma unroll
        for (int k = 0; k < 16; ++k) { accA[k] = sb2[jc * 16 + k]; accB[k] = accA[k]; }
#pragma unroll 4
        for (int i = 0; i < 64; ++i) {       // ROLLED (unroll 4): I$-safe
            const u32 hw = sh1[i * 128 + tid];
            const float aA = blo(hw), aB = bhi(hw);
            const float4* w4 = (const float4*)(sW2 + i * 64 + jc * 16);
#pragma unroll
            for (int k4 = 0; k4 < 4; ++k4) {
                float4 ww = w4[k4];
                accA[4 * k4 + 0] += aA * ww.x; accB[4 * k4 + 0] += aB * ww.x;
                accA[4 * k4 + 1] += aA * ww.y; accB[4 * k4 + 1] += aB * ww.y;
                accA[4 * k4 + 2] += aA * ww.z; accB[4 * k4 + 2] += aB * ww.z;
                accA[4 * k4 + 3] += aA * ww.w; accB[4 * k4 + 3] += aB * ww.w;
            }
        }
#pragma unroll
        for (int k = 0; k < 16; ++k) {       // h2 stays f32: numerics unchanged
            const float hA = swishf(accA[k]);
            const float hB = swishf(accB[k]);
            const float4* w4 = (const float4*)(sW3 + (jc * 16 + k) * 52);
#pragma unroll
            for (int v4 = 0; v4 < 13; ++v4) {
                float4 w = w4[v4];
                rA[4 * v4 + 0] += hA * w.x; rB[4 * v4 + 0] += hB * w.x;
                rA[4 * v4 + 1] += hA * w.y; rB[4 * v4 + 1] += hB * w.y;
                rA[4 * v4 + 2] += hA * w.z; rB[4 * v4 + 2] += hB * w.z;
                rA[4 * v4 + 3] += hA * w.w; rB[4 * v4 + 3] += hB * w.w;
            }
        }
    }

    // cached stores (L2 write-combines; round-5 proven WRITE ~= ideal)
    if (idxA < twoN) {
        const int n = idxA >> 1, mod = idxA & 1;
        const size_t ro = (size_t)n * 102 + (size_t)mod * 51;
#pragma unroll
        for (int v = 0; v < 51; ++v) stv(out, ro + v, isb, rA[v]);
    }
    if (idxB < twoN) {
        const int n = idxB >> 1, mod = idxB & 1;
        const size_t ro = (size_t)n * 102 + (size_t)mod * 51;
#pragma unroll
        for (int v = 0; v < 51; ++v) stv(out, ro + v, isb, rB[v]);
    }
}

extern "C" void kernel_launch(void* const* d_in, const int* in_sizes, int n_in,
                              void* d_out, int out_size, void* d_ws, size_t ws_size,
                              hipStream_t stream) {
    const int N = in_sizes[0] / 2;
    const void* obs      = d_in[0];
    const void* p        = d_in[1];
    const void* eps_skip = d_in[2];
    const void* eps_poe  = d_in[3];
    const int*  nbs      = (const int*)d_in[4];
    const int*  nbo      = (const int*)d_in[5];

    int* flag = (int*)d_ws;                                   // 64-byte flag region
    u16* gt   = (u16*)d_ws + 32;                              // gather table, N*64 bytes
    float* zbuf = (float*)((char*)d_ws + 64 + (size_t)N * 64); // z stash, 2N*6 f32

    dim3 grdA((N + 255) / 256);        // 256 samples per 128-thread block (S=2)
    dim3 grdP((2 * N + 255) / 256);    // k_poe: 256 threads, 1 pair each
    dim3 grdD((2 * N + 255) / 256);    // 256 pairs per 128-thread block (S=2)
    hipLaunchKernelGGL(k_detect, dim3(1), dim3(64), 0, stream,
                       (const unsigned int*)obs, flag);
    hipLaunchKernelGGL(k_encode, grdA, dim3(128), 0, stream,
                       obs, d_in[6], d_in[7], d_in[8], d_in[9], d_in[10], d_in[11],
                       flag, gt, N);
    hipLaunchKernelGGL(k_poe, grdP, dim3(256), 0, stream,
                       p, eps_skip, eps_poe, nbs, nbo,
                       flag, gt, zbuf, (void*)d_out, N);
    hipLaunchKernelGGL(k_decode, grdD, dim3(128), 0, stream,
                       d_in[12], d_in[13], d_in[14], d_in[15], d_in[16], d_in[17],
                       flag, zbuf, (void*)d_out, N);
}

// Round 7
// 1233.046 us; speedup vs baseline: 1.8802x; 1.1470x over previous
//
#include <hip/hip_runtime.h>
#include <hip/hip_bf16.h>

// MVAE fused pipeline, round 8 RESUBMIT (round-6 bench was the same infra
// failure as round 3: "container failed twice" at acquire, no pytest/absmax/
// profile. Round-3's identical failure passed on unchanged resubmit.
// Re-audit: LDS 56.4KB/64.7KB < 64KiB, hp2[64] static-indexed only, bounds
// clamps identical to passing round-7 run. Resubmitting unchanged.)
//
// Round-7 post-mortem: __launch_bounds__(128,1) changed NOTHING (VGPR 256,
// WRITE 675MB, 678us). Lesson: arch VGPRs hard-cap at 256 (v0..v255 encoding);
// the 512 figure is arch+AGPR unified, and non-MFMA kernels spill to SCRATCH,
// not AGPR. Fix must reduce peak live set, not raise the cap.
// Root cause of spill: rA[52]+rB[52] (104) live ACROSS the L2 i-loop which
// itself needs acc(32)+in-flight weights(~64)+temps -> ~240+ live.
// Restructure: (1) L2 phase accumulates h2 into hp2[64] packed-bf16 regs
// (jc loop fully unrolled -> static indexing); (2) write hp2 into sh1 (h1
// fully consumed; own-column, no barrier -- sh1 is per-thread private
// storage); (3) L3 phase reads h2 back via ds_read_b32 (2-way bank alias =
// free) with only rA/rB live. No phase exceeds ~160 VGPRs. Same skeleton
// for k_encode. h2 passes through bf16 like h1 already does (same rounding
// class, absmax unchanged). k_poe/k_detect untouched.
// ws layout: [0..63B] dtype flag, [64B..] gt (N*64B), then zbuf (2N*6 f32).

typedef unsigned short u16;
typedef unsigned int u32;
typedef __hip_bfloat16 bf16;
typedef int iv4 __attribute__((ext_vector_type(4)));

__device__ __forceinline__ float blo(u32 x) {
    union { u32 i; float f; } v; v.i = x << 16; return v.f;
}
__device__ __forceinline__ float bhi(u32 x) {
    union { u32 i; float f; } v; v.i = x & 0xffff0000u; return v.f;
}
__device__ __forceinline__ u16 f2b16(float f) {
    __hip_bfloat16 h = __float2bfloat16(f);
    u16 u; __builtin_memcpy(&u, &h, 2); return u;
}
__device__ __forceinline__ u32 pk2(float a, float b) {
    return (u32)f2b16(a) | ((u32)f2b16(b) << 16);
}
__device__ __forceinline__ float swishf(float x) {
    return x / (1.0f + __expf(-x));
}
// dtype-flexible load/store (isb is wave-uniform -> scalar branch)
__device__ __forceinline__ float ldv(const void* p, size_t i, int isb) {
    return isb ? __bfloat162float(((const bf16*)p)[i]) : ((const float*)p)[i];
}
__device__ __forceinline__ void stv(void* p, size_t i, int isb, float v) {
    if (isb) ((bf16*)p)[i] = __float2bfloat16(v);
    else     ((float*)p)[i] = v;
}
// nontemporal READ variant for streaming (read-once) traffic only
__device__ __forceinline__ float ldv_nt(const void* p, size_t i, int isb) {
    if (isb) { u16 b = __builtin_nontemporal_load((const u16*)p + i);
               union { u32 i; float f; } v; v.i = ((u32)b) << 16; return v.f; }
    return __builtin_nontemporal_load((const float*)p + i);
}

// ---------------- Kernel 0: dtype detect ----------------
__global__ void k_detect(const u32* __restrict__ obsw, int* __restrict__ flag) {
    u32 w = obsw[threadIdx.x];
    u32 e = (w >> 7) & 0xFFu;
    bool sane = (e >= 0x70u && e <= 0x87u);
    unsigned long long m = __ballot(sane);
    if (threadIdx.x == 0) flag[0] = (__popcll(m) >= 40) ? 1 : 0;
}

// ---------------- Kernel A: encoder (128 thr, S=2, phase-separated) ----------------
__global__ __launch_bounds__(128) void k_encode(
    const void* __restrict__ obs,
    const void* __restrict__ We1, const void* __restrict__ be1,
    const void* __restrict__ We2, const void* __restrict__ be2,
    const void* __restrict__ We3, const void* __restrict__ be3,
    const int* __restrict__ flag, u16* __restrict__ gt, int N)
{
    __shared__ float sW1[2 * 64];
    __shared__ float sb1[64];
    __shared__ float sW2[64 * 64];
    __shared__ float sb2[64];
    __shared__ float sW3[64 * 24];
    __shared__ float sb3[24];
    __shared__ u32 sh1[64 * 128];   // per-thread private column storage
    const int isb = flag[0];
    const int tid = threadIdx.x;
    for (int i = tid; i < 128; i += 128) sW1[i] = ldv(We1, i, isb);
    if (tid < 64) sb1[tid] = ldv(be1, tid, isb);
    for (int i = tid; i < 4096; i += 128) sW2[i] = ldv(We2, i, isb);
    if (tid < 64) sb2[tid] = ldv(be2, tid, isb);
    for (int i = tid; i < 1536; i += 128) sW3[i] = ldv(We3, i, isb);
    if (tid < 24) sb3[tid] = ldv(be3, tid, isb);
    __syncthreads();

    const int base = blockIdx.x * 256;
    const int nA = base + tid;
    const int nB = base + 128 + tid;
    const int nAc = nA < N ? nA : N - 1;
    const int nBc = nB < N ? nB : N - 1;

    const float a0 = ldv_nt(obs, 2 * (size_t)nAc, isb);
    const float a1 = ldv_nt(obs, 2 * (size_t)nAc + 1, isb);
    const float b0 = ldv_nt(obs, 2 * (size_t)nBc, isb);
    const float b1 = ldv_nt(obs, 2 * (size_t)nBc + 1, isb);

    // L1: 2 -> 64, packed pair straight to LDS (own column, no barrier)
#pragma unroll 4
    for (int j = 0; j < 64; ++j) {
        float w0 = sW1[j], w1 = sW1[64 + j], bb = sb1[j];
        float vA = swishf(a0 * w0 + a1 * w1 + bb);
        float vB = swishf(b0 * w0 + b1 * w1 + bb);
        sh1[j * 128 + tid] = pk2(vA, vB);
    }

    // L2 phase: h2 -> hp2[64] packed regs (jc unrolled -> static index)
    u32 hp2[64];
#pragma unroll
    for (int jc = 0; jc < 4; ++jc) {
        float accA[16], accB[16];
#pragma unroll
        for (int k = 0; k < 16; ++k) { accA[k] = sb2[jc * 16 + k]; accB[k] = accA[k]; }
#pragma unroll 4
        for (int i = 0; i < 64; ++i) {
            const u32 hw = sh1[i * 128 + tid];
            const float aA = blo(hw), aB = bhi(hw);
            const float4* w4 = (const float4*)(sW2 + i * 64 + jc * 16);
#pragma unroll
            for (int k4 = 0; k4 < 4; ++k4) {
                float4 ww = w4[k4];
                accA[4 * k4 + 0] += aA * ww.x; accB[4 * k4 + 0] += aB * ww.x;
                accA[4 * k4 + 1] += aA * ww.y; accB[4 * k4 + 1] += aB * ww.y;
                accA[4 * k4 + 2] += aA * ww.z; accB[4 * k4 + 2] += aB * ww.z;
                accA[4 * k4 + 3] += aA * ww.w; accB[4 * k4 + 3] += aB * ww.w;
            }
        }
#pragma unroll
        for (int k = 0; k < 16; ++k)
            hp2[jc * 16 + k] = pk2(swishf(accA[k]), swishf(accB[k]));
    }

    // overwrite sh1 with packed h2 (h1 fully consumed; own column)
#pragma unroll
    for (int k = 0; k < 64; ++k) sh1[k * 128 + tid] = hp2[k];

    // L3 phase: only oA/oB live
    float oA[24], oB[24];
#pragma unroll
    for (int v = 0; v < 24; ++v) { oA[v] = sb3[v]; oB[v] = sb3[v]; }
#pragma unroll 2
    for (int k = 0; k < 64; ++k) {
        const u32 hw = sh1[k * 128 + tid];
        const float hA = blo(hw), hB = bhi(hw);
        const float4* w4 = (const float4*)(sW3 + k * 24);
#pragma unroll
        for (int v4 = 0; v4 < 6; ++v4) {
            float4 w = w4[v4];
            oA[4 * v4 + 0] += hA * w.x; oB[4 * v4 + 0] += hB * w.x;
            oA[4 * v4 + 1] += hA * w.y; oB[4 * v4 + 1] += hB * w.y;
            oA[4 * v4 + 2] += hA * w.z; oB[4 * v4 + 2] += hB * w.z;
            oA[4 * v4 + 3] += hA * w.w; oB[4 * v4 + 3] += hB * w.w;
        }
    }

    // pack gather-table entries for each valid sample
    if (nA < N) {
        u16* g = gt + (size_t)nA * 32;
#pragma unroll
        for (int mod = 0; mod < 2; ++mod) {
            u32 pkk[8];
#pragma unroll
            for (int l = 0; l < 3; ++l)
                pkk[l] = pk2(oA[mod * 6 + 2 * l], oA[mod * 6 + 2 * l + 1]);
#pragma unroll
            for (int l = 0; l < 3; ++l)
                pkk[3 + l] = pk2(oA[12 + mod * 6 + 2 * l], oA[12 + mod * 6 + 2 * l + 1]);
            pkk[6] = 0u; pkk[7] = 0u;
            *(int4*)(g + mod * 16)     = make_int4(pkk[0], pkk[1], pkk[2], pkk[3]);
            *(int4*)(g + mod * 16 + 8) = make_int4(pkk[4], pkk[5], pkk[6], pkk[7]);
        }
    }
    if (nB < N) {
        u16* g = gt + (size_t)nB * 32;
#pragma unroll
        for (int mod = 0; mod < 2; ++mod) {
            u32 pkk[8];
#pragma unroll
            for (int l = 0; l < 3; ++l)
                pkk[l] = pk2(oB[mod * 6 + 2 * l], oB[mod * 6 + 2 * l + 1]);
#pragma unroll
            for (int l = 0; l < 3; ++l)
                pkk[3 + l] = pk2(oB[12 + mod * 6 + 2 * l], oB[12 + mod * 6 + 2 * l + 1]);
            pkk[6] = 0u; pkk[7] = 0u;
            *(int4*)(g + mod * 16)     = make_int4(pkk[0], pkk[1], pkk[2], pkk[3]);
            *(int4*)(g + mod * 16 + 8) = make_int4(pkk[4], pkk[5], pkk[6], pkk[7]);
        }
    }
}

// ---------------- Kernel B1: PoE / reparameterize (no LDS, high occ) ----------------
__global__ __launch_bounds__(256, 4) void k_poe(
    const void* __restrict__ p,
    const void* __restrict__ eps_skip, const void* __restrict__ eps_poe,
    const int* __restrict__ nbs, const int* __restrict__ nbo,
    const int* __restrict__ flag, const u16* __restrict__ gt,
    float* __restrict__ zbuf, void* __restrict__ out, int N)
{
    const int isb = flag[0];
    const int idx = blockIdx.x * 256 + threadIdx.x;   // over 2N (n,mod) pairs
    const int n = idx >> 1;
    const int mod = idx & 1;
    if (n >= N) return;

    const bool skip = ldv_nt(p, n, isb) < 0.5f;

    const u16* g = gt + (size_t)n * 32 + mod * 16;
    int4 sa = *(const int4*)g;
    int2 sbv = *(const int2*)(g + 8);
    float mu[6], lv[6];
    mu[0] = blo(sa.x); mu[1] = bhi(sa.x); mu[2] = blo(sa.y);
    mu[3] = bhi(sa.y); mu[4] = blo(sa.z); mu[5] = bhi(sa.z);
    lv[0] = blo(sa.w); lv[1] = bhi(sa.w); lv[2] = blo(sbv.x);
    lv[3] = bhi(sbv.x); lv[4] = blo(sbv.y); lv[5] = bhi(sbv.y);

    float z[6], outmu[6], outlv[6];

    if (!skip) {
        float sT[6], sM[6];
        const float priorT = 1.0f / (1.0f + 1e-8f);
#pragma unroll
        for (int l = 0; l < 6; ++l) {
            float T = 1.0f / (__expf(lv[l]) + 1e-8f);
            sT[l] = priorT + T;
            sM[l] = mu[l] * T;
        }
        const iv4* ps = (const iv4*)(nbs + (size_t)idx * 64);
        const iv4* po = (const iv4*)(nbo + (size_t)idx * 64);
#pragma unroll 4
        for (int k4 = 0; k4 < 16; ++k4) {
            iv4 s4 = __builtin_nontemporal_load(ps + k4);   // streaming: keep out of L2/L3
            iv4 o4 = __builtin_nontemporal_load(po + k4);
            int ss[4] = { s4[0], s4[1], s4[2], s4[3] };
            int oo[4] = { o4[0], o4[1], o4[2], o4[3] };
#pragma unroll
            for (int u = 0; u < 4; ++u) {
                int sidx = ss[u]; if ((unsigned)sidx >= (unsigned)N) sidx = 0;
                int oidx = oo[u] & 1;
                const u16* e = gt + (size_t)sidx * 32 + oidx * 16;  // hot table: cached
                int4 a = *(const int4*)e;
                int2 b = *(const int2*)(e + 8);
                float m0 = blo(a.x), m1 = bhi(a.x), m2 = blo(a.y);
                float m3 = bhi(a.y), m4 = blo(a.z), m5 = bhi(a.z);
                float v0 = blo(a.w), v1 = bhi(a.w), v2 = blo(b.x);
                float v3 = bhi(b.x), v4 = blo(b.y), v5 = bhi(b.y);
                float T0 = 1.0f / (__expf(v0) + 1e-8f); sT[0] += T0; sM[0] += m0 * T0;
                float T1 = 1.0f / (__expf(v1) + 1e-8f); sT[1] += T1; sM[1] += m1 * T1;
                float T2 = 1.0f / (__expf(v2) + 1e-8f); sT[2] += T2; sM[2] += m2 * T2;
                float T3 = 1.0f / (__expf(v3) + 1e-8f); sT[3] += T3; sM[3] += m3 * T3;
                float T4 = 1.0f / (__expf(v4) + 1e-8f); sT[4] += T4; sM[4] += m4 * T4;
                float T5 = 1.0f / (__expf(v5) + 1e-8f); sT[5] += T5; sM[5] += m5 * T5;
            }
        }
#pragma unroll
        for (int l = 0; l < 6; ++l) {
            float pm = sM[l] / sT[l];
            outmu[l] = pm;
            outlv[l] = -__logf(sT[l]);
            z[l] = pm + ldv_nt(eps_poe, (size_t)idx * 6 + l, isb) * rsqrtf(sT[l]);
        }
    } else {
#pragma unroll
        for (int l = 0; l < 6; ++l) {
            outmu[l] = mu[l];
            outlv[l] = lv[l];
            z[l] = mu[l] + ldv_nt(eps_skip, (size_t)idx * 6 + l, isb) * __expf(0.5f * lv[l]);
        }
    }

    // z stash for k_decode (cached: reread within ~100us)
#pragma unroll
    for (int l = 0; l < 6; ++l) zbuf[(size_t)idx * 6 + l] = z[l];

    // cached stores: L2 write-combines the lane-strided scalars (round-3/5 proven)
    const size_t om = (size_t)N * 102 + (size_t)idx * 6;
    const size_t ol = (size_t)N * 114 + (size_t)idx * 6;
#pragma unroll
    for (int l = 0; l < 6; ++l) {
        stv(out, om + l, isb, outmu[l]);
        stv(out, ol + l, isb, outlv[l]);
    }
}

// ---------------- Kernel B2: decoder (128 thr, S=2, phase-separated) ----------------
__global__ __launch_bounds__(128) void k_decode(
    const void* __restrict__ Wd1, const void* __restrict__ bd1,
    const void* __restrict__ Wd2, const void* __restrict__ bd2,
    const void* __restrict__ Wd3, const void* __restrict__ bd3,
    const int* __restrict__ flag, const float* __restrict__ zbuf,
    void* __restrict__ out, int N)
{
    __shared__ float sW1[6 * 64];
    __shared__ float sb1[64];
    __shared__ float sW2[64 * 64];
    __shared__ float sb2[64];
    __shared__ float sW3[64 * 52];   // rows padded 51->52
    __shared__ float sb3[52];
    __shared__ u32 sh1[64 * 128];    // per-thread private column storage
    const int isb = flag[0];
    const int tid = threadIdx.x;
    for (int i = tid; i < 384; i += 128) sW1[i] = ldv(Wd1, i, isb);
    if (tid < 64) sb1[tid] = ldv(bd1, tid, isb);
    for (int i = tid; i < 4096; i += 128) sW2[i] = ldv(Wd2, i, isb);
    if (tid < 64) sb2[tid] = ldv(bd2, tid, isb);
    for (int t = tid; t < 64 * 52; t += 128) {
        int i = t / 52, v = t - i * 52;
        sW3[t] = (v < 51) ? ldv(Wd3, i * 51 + v, isb) : 0.f;
    }
    if (tid < 52) sb3[tid] = (tid < 51) ? ldv(bd3, tid, isb) : 0.f;
    __syncthreads();

    const int twoN = 2 * N;
    const int base = blockIdx.x * 256;
    const int idxA = base + tid;
    const int idxB = base + 128 + tid;
    const int iAc = idxA < twoN ? idxA : twoN - 1;
    const int iBc = idxB < twoN ? idxB : twoN - 1;

    float zA[6], zB[6];
#pragma unroll
    for (int l = 0; l < 6; ++l) {
        zA[l] = zbuf[(size_t)iAc * 6 + l];
        zB[l] = zbuf[(size_t)iBc * 6 + l];
    }

    // L1: z -> h1, packed pair to LDS (own column, no barrier needed)
#pragma unroll 4
    for (int j4 = 0; j4 < 16; ++j4) {
        float A0 = sb1[4 * j4 + 0], A1 = sb1[4 * j4 + 1];
        float A2 = sb1[4 * j4 + 2], A3 = sb1[4 * j4 + 3];
        float B0 = A0, B1 = A1, B2 = A2, B3 = A3;
#pragma unroll
        for (int l = 0; l < 6; ++l) {
            float4 w = ((const float4*)(sW1 + l * 64))[j4];
            A0 += zA[l] * w.x; B0 += zB[l] * w.x;
            A1 += zA[l] * w.y; B1 += zB[l] * w.y;
            A2 += zA[l] * w.z; B2 += zB[l] * w.z;
            A3 += zA[l] * w.w; B3 += zB[l] * w.w;
        }
        sh1[(4 * j4 + 0) * 128 + tid] = pk2(swishf(A0), swishf(B0));
        sh1[(4 * j4 + 1) * 128 + tid] = pk2(swishf(A1), swishf(B1));
        sh1[(4 * j4 + 2) * 128 + tid] = pk2(swishf(A2), swishf(B2));
        sh1[(4 * j4 + 3) * 128 + tid] = pk2(swishf(A3), swishf(B3));
    }

    // L2 phase: h2 -> hp2[64] packed regs (jc unrolled -> static index)
    u32 hp2[64];
#pragma unroll
    for (int jc = 0; jc < 4; ++jc) {
        float accA[16], accB[16];
#pragma unroll
        for (int k = 0; k < 16; ++k) { accA[k] = sb2[jc * 16 + k]; accB[k] = accA[k]; }
#pragma unroll 4
        for (int i = 0; i < 64; ++i) {
            const u32 hw = sh1[i * 128 + tid];
            const float aA = blo(hw), aB = bhi(hw);
            const float4* w4 = (const float4*)(sW2 + i * 64 + jc * 16);
#pragma unroll
            for (int k4 = 0; k4 < 4; ++k4) {
                float4 ww = w4[k4];
                accA[4 * k4 + 0] += aA * ww.x; accB[4 * k4 + 0] += aB * ww.x;
                accA[4 * k4 + 1] += aA * ww.y; accB[4 * k4 + 1] += aB * ww.y;
                accA[4 * k4 + 2] += aA * ww.z; accB[4 * k4 + 2] += aB * ww.z;
                accA[4 * k4 + 3] += aA * ww.w; accB[4 * k4 + 3] += aB * ww.w;
            }
        }
#pragma unroll
        for (int k = 0; k < 16; ++k)
            hp2[jc * 16 + k] = pk2(swishf(accA[k]), swishf(accB[k]));
    }

    // overwrite sh1 with packed h2 (h1 fully consumed; own column)
#pragma unroll
    for (int k = 0; k < 64; ++k) sh1[k * 128 + tid] = hp2[k];

    // L3 phase: only rA/rB live
    float rA[52], rB[52];
#pragma unroll
    for (int v = 0; v < 52; ++v) { rA[v] = sb3[v]; rB[v] = sb3[v]; }
#pragma unroll 2
    for (int k = 0; k < 64; ++k) {
        const u32 hw = sh1[k * 128 + tid];
        const float hA = blo(hw), hB = bhi(hw);
        const float4* w4 = (const float4*)(sW3 + k * 52);
#pragma unroll
        for (int v4 = 0; v4 < 13; ++v4) {
            float4 w = w4[v4];
            rA[4 * v4 + 0] += hA * w.x; rB[4 * v4 + 0] += hB * w.x;
            rA[4 * v4 + 1] += hA * w.y; rB[4 * v4 + 1] += hB * w.y;
            rA[4 * v4 + 2] += hA * w.z; rB[4 * v4 + 2] += hB * w.z;
            rA[4 * v4 + 3] += hA * w.w; rB[4 * v4 + 3] += hB * w.w;
        }
    }

    // cached stores (L2 write-combines; round-5 proven WRITE ~= ideal)
    if (idxA < twoN) {
        const int n = idxA >> 1, mod = idxA & 1;
        const size_t ro = (size_t)n * 102 + (size_t)mod * 51;
#pragma unroll
        for (int v = 0; v < 51; ++v) stv(out, ro + v, isb, rA[v]);
    }
    if (idxB < twoN) {
        const int n = idxB >> 1, mod = idxB & 1;
        const size_t ro = (size_t)n * 102 + (size_t)mod * 51;
#pragma unroll
        for (int v = 0; v < 51; ++v) stv(out, ro + v, isb, rB[v]);
    }
}

extern "C" void kernel_launch(void* const* d_in, const int* in_sizes, int n_in,
                              void* d_out, int out_size, void* d_ws, size_t ws_size,
                              hipStream_t stream) {
    const int N = in_sizes[0] / 2;
    const void* obs      = d_in[0];
    const void* p        = d_in[1];
    const void* eps_skip = d_in[2];
    const void* eps_poe  = d_in[3];
    const int*  nbs      = (const int*)d_in[4];
    const int*  nbo      = (const int*)d_in[5];

    int* flag = (int*)d_ws;                                   // 64-byte flag region
    u16* gt   = (u16*)d_ws + 32;                              // gather table, N*64 bytes
    float* zbuf = (float*)((char*)d_ws + 64 + (size_t)N * 64); // z stash, 2N*6 f32

    dim3 grdA((N + 255) / 256);        // 256 samples per 128-thread block (S=2)
    dim3 grdP((2 * N + 255) / 256);    // k_poe: 256 threads, 1 pair each
    dim3 grdD((2 * N + 255) / 256);    // 256 pairs per 128-thread block (S=2)
    hipLaunchKernelGGL(k_detect, dim3(1), dim3(64), 0, stream,
                       (const unsigned int*)obs, flag);
    hipLaunchKernelGGL(k_encode, grdA, dim3(128), 0, stream,
                       obs, d_in[6], d_in[7], d_in[8], d_in[9], d_in[10], d_in[11],
                       flag, gt, N);
    hipLaunchKernelGGL(k_poe, grdP, dim3(256), 0, stream,
                       p, eps_skip, eps_poe, nbs, nbo,
                       flag, gt, zbuf, (void*)d_out, N);
    hipLaunchKernelGGL(k_decode, grdD, dim3(128), 0, stream,
                       d_in[12], d_in[13], d_in[14], d_in[15], d_in[16], d_in[17],
                       flag, zbuf, (void*)d_out, N);
}